// Round 5
// baseline (7688.150 us; speedup 1.0000x reference)
//
#include <hip/hip_runtime.h>
#include <math.h>

// Problem constants
#define NN 4096
#define TT 48
#define HH 64
#define GG 256   // 4*H
#define PP 12
#define CAP 192  // ELL slots per row, 3 x 64 -> whole-wave chunk loads, no guard
#define NH (NN * HH)

// readlane broadcast: uniform lane index -> SGPR broadcast, off the LDS pipe
__device__ __forceinline__ float bcast_f(float v, int lane) {
  return __int_as_float(__builtin_amdgcn_readlane(__float_as_int(v), lane));
}
__device__ __forceinline__ int bcast_i(int v, int lane) {
  return __builtin_amdgcn_readlane(v, lane);
}

// ---------------------------------------------------------------------------
// h-state: paired buffers P[2], each [N][64][2]: {h0, h1} interleaved.
// Launch k (k=0..48) computes cell0(t=k) [k<48] and cell1(s=k-1) [k>0]:
//   READS only P[(k&1)^1]  (cell0: .x = h0(k-1); cell1: {h0(k-1), h1(k-2)})
//   WRITES only P[k&1]     (cell0 -> .x = h0(k);  cell1 -> .y = h1(k-1))
// Different 4B slots of the same float2 -> no intra-launch hazard; the two
// roles are mutually independent => one fused launch. Final h1(47) in P[0].y.
//
// R4: R0 structure (1024 blocks x 4 waves x 2 rows, 16 waves/CU -- the
// proven TLP point) + DOUBLE-BUFFERED LDS weight staging. History:
//   R0 48.5us: per-wave weight re-stream 768 MB/launch through L2 (~22us)
//              added to ~22us VALU, poor overlap (46% VALUBusy).
//   R1 59us:   8 waves/SIMD + forced VGPR 32 -> spills; occupancy not the
//              limiter (VALUBusy unchanged at 47%).
//   R2 66.5us: bytes/4 via 8 rows/wave but 1 wave/SIMD -> latency exposed
//              (VALUBusy 30%).
//   R3 61.4us: LDS staging SINGLE-buffered: stage between two barriers ->
//              transfer serialized with compute (VALUBusy 36%).
// Fix: ping-pong 2 x 16 KB chunks. Top of chunk ch: issue global loads of
// chunk ch+1 into regs; compute ch from LDS (covers L2 latency); write regs
// -> other buffer; ONE barrier per chunk. Chunk-0 loads issued before the
// gather phase (latency hides under gather). Weight L2 bytes /4
// (768 -> 192 MB/launch ~ 6us), transfer overlapped. FP order bit-identical
// to R0 -> absmax 0. 32 KB LDS -> 4 blocks/CU kept; +16 VGPR staging regs
// (must stay <=128 for 16 waves/CU).
//
// GATE-QUAD mapping: lane j owns cols {j, j+64, j+128, j+192} = (i,f,o,g) of
// hidden unit j. One wave = 2 rows x 256 cols; full quad in one lane's
// float4 acc.
//   Wg0[(k*2+m)*64+j] = float4 gate-quad, m in {gcWh0, liWh0}
//   Wg1[(k*4+m)*64+j] = float4 gate-quad, m in {gcWi1, liWi1, gcWh1, liWh1}
// ---------------------------------------------------------------------------
__launch_bounds__(256)
__global__ void k_prep(const float* gcbi0, const float* gcbh0,
                       const float* libi0, const float* libh0,
                       const float* gcbi1, const float* gcbh1,
                       const float* libi1, const float* libh1,
                       const float* gcWh0, const float* liWh0,
                       const float* gcWi1, const float* liWi1,
                       const float* gcWh1, const float* liWh1,
                       const float* gcWi0, const float* liWi0,
                       float* state, float4* Wg0, float4* Wg1,
                       float4* biasg0, float4* biasg1, float4* xq0) {
  int idx = blockIdx.x * 256 + threadIdx.x;
  int stride = gridDim.x * 256;
  for (int i = idx; i < 6 * NH; i += stride) state[i] = 0.0f;  // P0,P1,c0,c1
  for (int i = idx; i < 64 * 2 * 64; i += stride) {
    int j = i & 63, m = (i >> 6) & 1, k = i >> 7;
    const float* W = m ? liWh0 : gcWh0;
    Wg0[i] = make_float4(W[k * GG + j], W[k * GG + j + 64],
                         W[k * GG + j + 128], W[k * GG + j + 192]);
  }
  for (int i = idx; i < 64 * 4 * 64; i += stride) {
    int j = i & 63, m = (i >> 6) & 3, k = i >> 8;
    const float* W = (m == 0) ? gcWi1 : (m == 1) ? liWi1 : (m == 2) ? gcWh1 : liWh1;
    Wg1[i] = make_float4(W[k * GG + j], W[k * GG + j + 64],
                         W[k * GG + j + 128], W[k * GG + j + 192]);
  }
  if (idx < 64) {
    int j = idx;
    biasg0[j] = make_float4(
        gcbi0[j] + gcbh0[j] + libi0[j] + libh0[j],
        gcbi0[j + 64] + gcbh0[j + 64] + libi0[j + 64] + libh0[j + 64],
        gcbi0[j + 128] + gcbh0[j + 128] + libi0[j + 128] + libh0[j + 128],
        gcbi0[j + 192] + gcbh0[j + 192] + libi0[j + 192] + libh0[j + 192]);
    biasg1[j] = make_float4(
        gcbi1[j] + gcbh1[j] + libi1[j] + libh1[j],
        gcbi1[j + 64] + gcbh1[j + 64] + libi1[j + 64] + libh1[j + 64],
        gcbi1[j + 128] + gcbh1[j + 128] + libi1[j + 128] + libh1[j + 128],
        gcbi1[j + 192] + gcbh1[j + 192] + libi1[j + 192] + libh1[j + 192]);
  } else if (idx < 320) {
    int i = idx - 64;           // i = m*64 + j
    int j = i & 63, m = i >> 6; // m: 0,1 -> gcWi0 row 0/1; 2,3 -> liWi0 row 0/1
    const float* W = (m < 2) ? gcWi0 : liWi0;
    int kk = m & 1;
    xq0[i] = make_float4(W[kk * GG + j], W[kk * GG + j + 64],
                         W[kk * GG + j + 128], W[kk * GG + j + 192]);
  }
}

// ---------------------------------------------------------------------------
// Single adj pass: raw ELL (incl. +I diag) + dinv. Zero-fills ALL CAP slots
// (re-poison semantics: padding must be (col=0, val=0)). cnt padded to x8.
// ---------------------------------------------------------------------------
__launch_bounds__(256)
__global__ void k_build(const float* adj, float* dinv,
                        int* ell_col, float* ell_val, int* ell_cnt) {
  int r = blockIdx.x;
  __shared__ int cnt;
  __shared__ float red[256];
  if (threadIdx.x == 0) cnt = 0;
  __syncthreads();
  const float* row = adj + (size_t)r * NN;
  float s = 0.0f;
  for (int c = threadIdx.x; c < NN; c += 256) {
    float a = row[c];
    if (c == r) a += 1.0f;   // A = adj + I
    s += a;
    if (a != 0.0f) {
      int pos = atomicAdd(&cnt, 1);
      if (pos < CAP) {
        ell_col[(size_t)r * CAP + pos] = c;
        ell_val[(size_t)r * CAP + pos] = a;
      }
    }
  }
  red[threadIdx.x] = s;
  __syncthreads();
  for (int st = 128; st > 0; st >>= 1) {
    if (threadIdx.x < st) red[threadIdx.x] += red[threadIdx.x + st];
    __syncthreads();
  }
  int n = cnt < CAP ? cnt : CAP;
  for (int j = n + (int)threadIdx.x; j < CAP; j += 256) {
    ell_col[(size_t)r * CAP + j] = 0;
    ell_val[(size_t)r * CAP + j] = 0.0f;
  }
  if (threadIdx.x == 0) {
    int npad = (n + 7) & ~7;
    if (npad > CAP) npad = CAP;
    ell_cnt[r] = npad;
    dinv[r] = 1.0f / sqrtf(red[0]);  // rowsum + 1 >= 1
  }
}

__launch_bounds__(256)
__global__ void k_scale(const float* dinv, const int* ell_col, float* ell_val) {
  int idx = blockIdx.x * 256 + threadIdx.x;  // over NN*CAP
  int r = idx / CAP;
  if (r >= NN) return;
  float v = ell_val[idx];
  if (v != 0.0f) ell_val[idx] = v * dinv[r] * dinv[ell_col[idx]];
}

// ---------------------------------------------------------------------------
// Precompute gax[t][r][c] = (A @ x_t)[r][c]. Block = (t, 512-row segment).
// ---------------------------------------------------------------------------
__launch_bounds__(256)
__global__ void k_gax(const float* x, const int* ell_col, const float* ell_val,
                      const int* ell_cnt, float* gax) {
  int t = blockIdx.x >> 3;
  int seg = blockIdx.x & 7;
  __shared__ float xs[NN * 2];
  const float* xt = x + (size_t)t * NN * 2;
  for (int i = threadIdx.x; i < NN * 2; i += 256) xs[i] = xt[i];
  __syncthreads();
  int base = seg * 512 * 2;
  for (int oo = threadIdx.x; oo < 512 * 2; oo += 256) {
    int o = base + oo;
    int r = o >> 1, cmp = o & 1;
    int cnt = ell_cnt[r];
    const int* cp = ell_col + (size_t)r * CAP;
    const float* vp = ell_val + (size_t)r * CAP;
    float acc = 0.0f;
    for (int j = 0; j < cnt; j += 4) {
      acc += vp[j]     * xs[cp[j]     * 2 + cmp];
      acc += vp[j + 1] * xs[cp[j + 1] * 2 + cmp];
      acc += vp[j + 2] * xs[cp[j + 2] * 2 + cmp];
      acc += vp[j + 3] * xs[cp[j + 3] * 2 + cmp];
    }
    gax[(size_t)t * NN * 2 + o] = acc;
  }
}

// ---------------------------------------------------------------------------
// Cell 0 body (one block of 8 rows, 4 waves x 2 rows): gather from global
// (unchanged from R0); dense loop reads weights from double-buffered LDS.
// Chunk = 8 k's = 1024 float4 = 16 KB; 8 chunks; 1 barrier per chunk.
// ---------------------------------------------------------------------------
__device__ __forceinline__ void cell0_body(
    int blk, int tid,
    const int* __restrict__ ell_col, const float* __restrict__ ell_val,
    const int* __restrict__ ell_cnt,
    const float2* __restrict__ Pr, float* __restrict__ Pw,
    float* __restrict__ c0,
    const float* __restrict__ xt, const float* __restrict__ gaxt,
    const float4* __restrict__ Wg0, const float4* __restrict__ biasg0,
    const float4* __restrict__ xq0, float4* wbuf) {
  const int wave = tid >> 6, lane = tid & 63;
  const int r0 = blk * 8 + wave * 2;

  // issue chunk-0 loads NOW; they complete during the gather phase
  float4 st0 = Wg0[tid], st1 = Wg0[256 + tid],
         st2 = Wg0[512 + tid], st3 = Wg0[768 + tid];

  int myc[2][3]; float myv[2][3]; int cnts[2];
#pragma unroll
  for (int rr = 0; rr < 2; rr++) {
    int r = r0 + rr;
    cnts[rr] = ell_cnt[r];
#pragma unroll
    for (int chk = 0; chk < 3; chk++) {
      myc[rr][chk] = ell_col[(size_t)r * CAP + chk * 64 + lane];
      myv[rr][chk] = ell_val[(size_t)r * CAP + chk * 64 + lane];
    }
  }
  float gacc[2], hl[2];
#pragma unroll
  for (int rr = 0; rr < 2; rr++) {
    int cnt = cnts[rr];
    float acc = 0.0f;
#pragma unroll
    for (int chk = 0; chk < 3; chk++) {
      int base = chk * 64;
      if (base < cnt) {
        int lim = cnt - base; if (lim > 64) lim = 64;  // multiple of 8
        int mc = myc[rr][chk]; float mv = myv[rr][chk];
        for (int m = 0; m < lim; m += 8) {
          float2 ld[8]; float vv[8];
#pragma unroll
          for (int i = 0; i < 8; i++) {
            int cc = bcast_i(mc, m + i);
            vv[i] = bcast_f(mv, m + i);
            ld[i] = Pr[(size_t)cc * 64 + lane];
          }
#pragma unroll
          for (int i = 0; i < 8; i++) acc += vv[i] * ld[i].x;
        }
      }
    }
    gacc[rr] = acc;
    hl[rr] = Pr[(size_t)(r0 + rr) * 64 + lane].x;
  }

  float4 acc[2];
  {
    float4 b = biasg0[lane];
    float4 qg0 = xq0[lane], qg1 = xq0[64 + lane];
    float4 ql0 = xq0[128 + lane], ql1 = xq0[192 + lane];
#pragma unroll
    for (int rr = 0; rr < 2; rr++) {
      float xx0 = xt[(size_t)(r0 + rr) * 2];
      float xx1 = xt[(size_t)(r0 + rr) * 2 + 1];
      float gg0 = gaxt[(size_t)(r0 + rr) * 2];
      float gg1 = gaxt[(size_t)(r0 + rr) * 2 + 1];
      acc[rr].x = b.x + gg0 * qg0.x + gg1 * qg1.x + xx0 * ql0.x + xx1 * ql1.x;
      acc[rr].y = b.y + gg0 * qg0.y + gg1 * qg1.y + xx0 * ql0.y + xx1 * ql1.y;
      acc[rr].z = b.z + gg0 * qg0.z + gg1 * qg1.z + xx0 * ql0.z + xx1 * ql1.z;
      acc[rr].w = b.w + gg0 * qg0.w + gg1 * qg1.w + xx0 * ql0.w + xx1 * ql1.w;
    }
  }

  // write chunk 0 and enter the ping-pong loop
  wbuf[tid] = st0; wbuf[256 + tid] = st1;
  wbuf[512 + tid] = st2; wbuf[768 + tid] = st3;
  __syncthreads();
  int cur = 0;
  for (int ch = 0; ch < 8; ch++) {
    bool pf = (ch + 1 < 8);
    if (pf) {  // issue next-chunk loads; compute below covers their latency
      const float4* src = Wg0 + (ch + 1) * 1024 + tid;
      st0 = src[0]; st1 = src[256]; st2 = src[512]; st3 = src[768];
    }
    const float4* wb = wbuf + (cur << 10);
#pragma unroll
    for (int kk = 0; kk < 8; kk++) {
      int k = ch * 8 + kk;
      float4 w0 = wb[(kk * 2 + 0) * 64 + lane];
      float4 w1 = wb[(kk * 2 + 1) * 64 + lane];
#pragma unroll
      for (int rr = 0; rr < 2; rr++) {
        float a0 = bcast_f(gacc[rr], k);
        float a1 = bcast_f(hl[rr], k);
        acc[rr].x += a0 * w0.x + a1 * w1.x;
        acc[rr].y += a0 * w0.y + a1 * w1.y;
        acc[rr].z += a0 * w0.z + a1 * w1.z;
        acc[rr].w += a0 * w0.w + a1 * w1.w;
      }
    }
    if (pf) {
      cur ^= 1;
      float4* dst = wbuf + (cur << 10) + tid;
      dst[0] = st0; dst[256] = st1; dst[512] = st2; dst[768] = st3;
      __syncthreads();  // writes visible; all waves past chunk ch
    }
  }

#pragma unroll
  for (int rr = 0; rr < 2; rr++) {
    size_t gi = (size_t)(r0 + rr) * HH + lane;
    float cprev = c0[gi];
    float si = 1.0f / (1.0f + __expf(-acc[rr].x));
    float sf = 1.0f / (1.0f + __expf(-acc[rr].y));
    float so = 1.0f / (1.0f + __expf(-acc[rr].z));
    float cn = sf * cprev + si * tanhf(acc[rr].w);
    float hn = so * tanhf(cn);
    c0[gi] = cn;
    Pw[gi * 2 + 0] = hn;
  }
}

// ---------------------------------------------------------------------------
// Cell 1 body (one block of 8 rows): dual gather from paired {h0n,h1old};
// dense loop from double-buffered LDS. Chunk = 4 k's = 16 KB; 16 chunks.
// ---------------------------------------------------------------------------
__device__ __forceinline__ void cell1_body(
    int blk, int tid,
    const int* __restrict__ ell_col, const float* __restrict__ ell_val,
    const int* __restrict__ ell_cnt,
    const float2* __restrict__ Pr, float* __restrict__ Pw,
    float* __restrict__ c1,
    const float4* __restrict__ Wg1, const float4* __restrict__ biasg1,
    float4* wbuf) {
  const int wave = tid >> 6, lane = tid & 63;
  const int r0 = blk * 8 + wave * 2;

  // issue chunk-0 loads NOW; they complete during the gather phase
  float4 st0 = Wg1[tid], st1 = Wg1[256 + tid],
         st2 = Wg1[512 + tid], st3 = Wg1[768 + tid];

  int myc[2][3]; float myv[2][3]; int cnts[2];
#pragma unroll
  for (int rr = 0; rr < 2; rr++) {
    int r = r0 + rr;
    cnts[rr] = ell_cnt[r];
#pragma unroll
    for (int chk = 0; chk < 3; chk++) {
      myc[rr][chk] = ell_col[(size_t)r * CAP + chk * 64 + lane];
      myv[rr][chk] = ell_val[(size_t)r * CAP + chk * 64 + lane];
    }
  }
  float ga0[2], ga1[2], hl0[2], hl1[2];
#pragma unroll
  for (int rr = 0; rr < 2; rr++) {
    int cnt = cnts[rr];
    float a0 = 0.0f, a1 = 0.0f;
#pragma unroll
    for (int chk = 0; chk < 3; chk++) {
      int base = chk * 64;
      if (base < cnt) {
        int lim = cnt - base; if (lim > 64) lim = 64;  // multiple of 8
        int mc = myc[rr][chk]; float mv = myv[rr][chk];
        for (int m = 0; m < lim; m += 8) {
          float2 ld[8]; float vv[8];
#pragma unroll
          for (int i = 0; i < 8; i++) {
            int cc = bcast_i(mc, m + i);
            vv[i] = bcast_f(mv, m + i);
            ld[i] = Pr[(size_t)cc * 64 + lane];
          }
#pragma unroll
          for (int i = 0; i < 8; i++) {
            a0 += vv[i] * ld[i].x;
            a1 += vv[i] * ld[i].y;
          }
        }
      }
    }
    ga0[rr] = a0;
    ga1[rr] = a1;
    float2 hh = Pr[(size_t)(r0 + rr) * 64 + lane];
    hl0[rr] = hh.x;
    hl1[rr] = hh.y;
  }

  float4 acc[2];
  {
    float4 b = biasg1[lane];
    acc[0] = b; acc[1] = b;
  }

  // write chunk 0 and enter the ping-pong loop
  wbuf[tid] = st0; wbuf[256 + tid] = st1;
  wbuf[512 + tid] = st2; wbuf[768 + tid] = st3;
  __syncthreads();
  int cur = 0;
  for (int ch = 0; ch < 16; ch++) {
    bool pf = (ch + 1 < 16);
    if (pf) {
      const float4* src = Wg1 + (ch + 1) * 1024 + tid;
      st0 = src[0]; st1 = src[256]; st2 = src[512]; st3 = src[768];
    }
    const float4* wb = wbuf + (cur << 10);
#pragma unroll
    for (int kk = 0; kk < 4; kk++) {
      int k = ch * 4 + kk;
      float4 w0 = wb[(kk * 4 + 0) * 64 + lane];
      float4 w1 = wb[(kk * 4 + 1) * 64 + lane];
      float4 w2 = wb[(kk * 4 + 2) * 64 + lane];
      float4 w3 = wb[(kk * 4 + 3) * 64 + lane];
#pragma unroll
      for (int rr = 0; rr < 2; rr++) {
        float a0 = bcast_f(ga0[rr], k);   // (A@h0n)   -> gcWi1
        float a1 = bcast_f(hl0[rr], k);   // h0n       -> liWi1
        float a2 = bcast_f(ga1[rr], k);   // (A@h1old) -> gcWh1
        float a3 = bcast_f(hl1[rr], k);   // h1old     -> liWh1
        acc[rr].x += a0 * w0.x + a1 * w1.x + a2 * w2.x + a3 * w3.x;
        acc[rr].y += a0 * w0.y + a1 * w1.y + a2 * w2.y + a3 * w3.y;
        acc[rr].z += a0 * w0.z + a1 * w1.z + a2 * w2.z + a3 * w3.z;
        acc[rr].w += a0 * w0.w + a1 * w1.w + a2 * w2.w + a3 * w3.w;
      }
    }
    if (pf) {
      cur ^= 1;
      float4* dst = wbuf + (cur << 10) + tid;
      dst[0] = st0; dst[256] = st1; dst[512] = st2; dst[768] = st3;
      __syncthreads();  // writes visible; all waves past chunk ch
    }
  }

#pragma unroll
  for (int rr = 0; rr < 2; rr++) {
    size_t gi = (size_t)(r0 + rr) * HH + lane;
    float cprev = c1[gi];
    float si = 1.0f / (1.0f + __expf(-acc[rr].x));
    float sf = 1.0f / (1.0f + __expf(-acc[rr].y));
    float so = 1.0f / (1.0f + __expf(-acc[rr].z));
    float cn = sf * cprev + si * tanhf(acc[rr].w);
    float hn = so * tanhf(cn);
    c1[gi] = cn;
    Pw[gi * 2 + 1] = hn;
  }
}

// ---------------------------------------------------------------------------
// Fused step kernel: blocks [0, c0blocks) run cell0(t); the rest run
// cell1(t-1). The two roles are independent (see header comment): the launch
// reads only Pr and writes only Pw (disjoint float2 slots).
// 256 threads, 2 x 16 KB LDS ping-pong -> 4 blocks/CU (16 waves/CU).
// ---------------------------------------------------------------------------
__launch_bounds__(256)
__global__ void k_cells(int c0blocks,
                        const int* __restrict__ ell_col,
                        const float* __restrict__ ell_val,
                        const int* __restrict__ ell_cnt,
                        const float2* __restrict__ Pr, float* __restrict__ Pw,
                        float* __restrict__ c0, float* __restrict__ c1,
                        const float* __restrict__ xt, const float* __restrict__ gaxt,
                        const float4* __restrict__ Wg0,
                        const float4* __restrict__ biasg0,
                        const float4* __restrict__ xq0,
                        const float4* __restrict__ Wg1,
                        const float4* __restrict__ biasg1) {
  __shared__ float4 wbuf[2048];  // 2 x 16 KB ping-pong
  int b = blockIdx.x;
  if (b < c0blocks) {
    cell0_body(b, threadIdx.x, ell_col, ell_val, ell_cnt, Pr, Pw, c0, xt, gaxt,
               Wg0, biasg0, xq0, wbuf);
  } else {
    cell1_body(b - c0blocks, threadIdx.x, ell_col, ell_val, ell_cnt, Pr, Pw, c1,
               Wg1, biasg1, wbuf);
  }
}

// ---------------------------------------------------------------------------
// Output projection: out[r,p] = h1[r,:] @ outW[:,p] + outb[p].
// h1 final = P0[..][1] (launch 48 writes P[0].y).
// ---------------------------------------------------------------------------
__launch_bounds__(256)
__global__ void k_out(const float* __restrict__ P0, const float* __restrict__ outW,
                      const float* __restrict__ outb, float* __restrict__ out) {
  int idx = blockIdx.x * 256 + threadIdx.x;
  if (idx >= NN * PP) return;
  int r = idx / PP, p = idx - r * PP;
  float acc = outb[p];
  const float* hrow = P0 + (size_t)r * 128;
#pragma unroll 16
  for (int k = 0; k < HH; k++) acc += hrow[k * 2 + 1] * outW[k * PP + p];
  out[idx] = acc;
}

extern "C" void kernel_launch(void* const* d_in, const int* in_sizes, int n_in,
                              void* d_out, int out_size, void* d_ws, size_t ws_size,
                              hipStream_t stream) {
  const float* x     = (const float*)d_in[0];
  const float* adj   = (const float*)d_in[1];
  const float* gcWi0 = (const float*)d_in[2];
  const float* gcbi0 = (const float*)d_in[3];
  const float* gcWh0 = (const float*)d_in[4];
  const float* gcbh0 = (const float*)d_in[5];
  const float* liWi0 = (const float*)d_in[6];
  const float* libi0 = (const float*)d_in[7];
  const float* liWh0 = (const float*)d_in[8];
  const float* libh0 = (const float*)d_in[9];
  const float* gcWi1 = (const float*)d_in[10];
  const float* gcbi1 = (const float*)d_in[11];
  const float* gcWh1 = (const float*)d_in[12];
  const float* gcbh1 = (const float*)d_in[13];
  const float* liWi1 = (const float*)d_in[14];
  const float* libi1 = (const float*)d_in[15];
  const float* liWh1 = (const float*)d_in[16];
  const float* libh1 = (const float*)d_in[17];
  const float* outW  = (const float*)d_in[18];
  const float* outb  = (const float*)d_in[19];

  char* ws = (char*)d_ws;
  size_t off = 0;
  auto carve = [&](size_t bytes) {
    void* p = ws + off;
    off += (bytes + 255) & ~(size_t)255;
    return p;
  };
  float*  dinv    = (float*)carve((size_t)NN * 4);
  int*    ell_col = (int*)carve((size_t)NN * CAP * 4);
  float*  ell_val = (float*)carve((size_t)NN * CAP * 4);
  int*    ell_cnt = (int*)carve((size_t)NN * 4);
  float*  state   = (float*)carve((size_t)6 * NH * 4);  // P0,P1 (2NH each), c0, c1
  float*  gax     = (float*)carve((size_t)TT * NN * 2 * 4);
  float4* Wg0     = (float4*)carve((size_t)64 * 2 * 64 * 16);
  float4* Wg1     = (float4*)carve((size_t)64 * 4 * 64 * 16);
  float4* biasg0  = (float4*)carve((size_t)64 * 16);
  float4* biasg1  = (float4*)carve((size_t)64 * 16);
  float4* xq0     = (float4*)carve((size_t)256 * 16);

  float* P[2] = {state, state + 2 * NH};
  float* c0 = state + 4 * NH;
  float* c1 = state + 5 * NH;

  k_prep<<<512, 256, 0, stream>>>(gcbi0, gcbh0, libi0, libh0,
                                  gcbi1, gcbh1, libi1, libh1,
                                  gcWh0, liWh0, gcWi1, liWi1, gcWh1, liWh1,
                                  gcWi0, liWi0,
                                  state, Wg0, Wg1, biasg0, biasg1, xq0);
  k_build<<<NN, 256, 0, stream>>>(adj, dinv, ell_col, ell_val, ell_cnt);
  k_scale<<<(NN * CAP) / 256, 256, 0, stream>>>(dinv, ell_col, ell_val);
  k_gax<<<TT * 8, 256, 0, stream>>>(x, ell_col, ell_val, ell_cnt, gax);

  // Software-pipelined step loop: launch k runs {cell0(k) || cell1(k-1)}.
  // Launch k reads P[(k&1)^1], writes P[k&1].
  for (int k = 0; k <= TT; k++) {
    int A = k & 1;
    int c0blocks = (k < TT) ? NN / 8 : 0;          // cell0 active for k<48
    int c1blocks = (k > 0) ? NN / 8 : 0;           // cell1 active for k>0
    int grid = c0blocks + c1blocks;
    int tx = (k < TT) ? k : (TT - 1);              // xt/gaxt unused when k==TT
    k_cells<<<grid, 256, 0, stream>>>(
        c0blocks, ell_col, ell_val, ell_cnt,
        (const float2*)P[A ^ 1], P[A], c0, c1,
        x + (size_t)tx * NN * 2, gax + (size_t)tx * NN * 2,
        Wg0, biasg0, xq0, Wg1, biasg1);
  }

  // Launch 48 (A=0) wrote h1(47) into P[0].y
  k_out<<<(NN * PP + 255) / 256, 256, 0, stream>>>(P[0], outW, outb, (float*)d_out);
}

// Round 6
// 4858.615 us; speedup vs baseline: 1.5824x; 1.5824x over previous
//
#include <hip/hip_runtime.h>
#include <math.h>

// Problem constants
#define NN 4096
#define TT 48
#define HH 64
#define GG 256   // 4*H
#define PP 12
#define CAP 192  // ELL slots per row, 3 x 64 -> whole-wave chunk loads, no guard
#define NH (NN * HH)

// readlane broadcast: uniform lane index -> SGPR broadcast, off the LDS pipe
__device__ __forceinline__ float bcast_f(float v, int lane) {
  return __int_as_float(__builtin_amdgcn_readlane(__float_as_int(v), lane));
}
__device__ __forceinline__ int bcast_i(int v, int lane) {
  return __builtin_amdgcn_readlane(v, lane);
}

// global->LDS direct DMA: 64 lanes x 16 B = 1 KB per call, ZERO VGPR cost.
// lds dest must be wave-uniform base (+ lane*16 implicit), layout linear.
__device__ __forceinline__ void stage1k(const float4* gsrc, float4* ldst) {
  auto* g = (const __attribute__((address_space(1))) unsigned int*)(gsrc);
  auto* l = (__attribute__((address_space(3))) unsigned int*)(ldst);
  __builtin_amdgcn_global_load_lds(g, l, 16, 0, 0);
}

// ---------------------------------------------------------------------------
// h-state: paired buffers P[2], each [N][64][2]: {h0, h1} interleaved.
// Launch k (k=0..48) computes cell0(t=k) [k<48] and cell1(s=k-1) [k>0]:
//   READS only P[(k&1)^1]  (cell0: .x = h0(k-1); cell1: {h0(k-1), h1(k-2)})
//   WRITES only P[k&1]     (cell0 -> .x = h0(k);  cell1 -> .y = h1(k-1))
// Different 4B slots of the same float2 -> no intra-launch hazard; one fused
// launch per step. Final h1(47) in P[0].y.
//
// R5: R0 structure (1024 blocks x 4 waves x 2 rows, 16 waves/CU) + ping-pong
// LDS weight staging via __builtin_amdgcn_global_load_lds. History:
//   R0 48.5us: weights re-streamed per wave, 768 MB/launch L2 (~22-28us)
//              ADDED to ~20us VALU (46% VALUBusy).
//   R1 59us:   k-split occupancy push -> forced VGPR 32, spills. TLP not
//              the limiter.
//   R2 66.5us: 8 rows/wave cut bytes /4 but 1 wave/SIMD -> latency exposed.
//   R3 61.4us: LDS staging, single-buffered -> transfer between two
//              barriers, serialized (stage 2100cy vs compute 640cy/chunk).
//   R4 164us:  reg-staged double-buffer -> VGPR 256, ~250 MB/launch scratch
//              spill traffic. Schedule never tested.
// Fix: global_load_lds is tracked by vmcnt and costs no VGPRs; the
// __syncthreads() at chunk end drains it. Per chunk: issue DMA for ch+1
// into buf^1; compute ch from buf (covers DMA latency); ONE barrier; flip.
// Chunk-0 DMA issued before the gather phase -- vmcnt completion is
// in-order, so it lands before the gather's own loads complete (free).
// Weight L2 bytes /4 (768 -> 192 MB/launch). 2 x 16 KB chunks = 32 KB LDS
// -> 4 blocks/CU (16 waves/CU, R0's proven TLP). FP order per row
// identical to R0.
//
// GATE-QUAD mapping: lane j owns cols {j, j+64, j+128, j+192} = (i,f,o,g) of
// hidden unit j. One wave = 2 rows x 256 cols; full quad in one lane's
// float4 acc.
//   Wg0[(k*2+m)*64+j] = float4 gate-quad, m in {gcWh0, liWh0}
//   Wg1[(k*4+m)*64+j] = float4 gate-quad, m in {gcWi1, liWi1, gcWh1, liWh1}
// ---------------------------------------------------------------------------
__launch_bounds__(256)
__global__ void k_prep(const float* gcbi0, const float* gcbh0,
                       const float* libi0, const float* libh0,
                       const float* gcbi1, const float* gcbh1,
                       const float* libi1, const float* libh1,
                       const float* gcWh0, const float* liWh0,
                       const float* gcWi1, const float* liWi1,
                       const float* gcWh1, const float* liWh1,
                       const float* gcWi0, const float* liWi0,
                       float* state, float4* Wg0, float4* Wg1,
                       float4* biasg0, float4* biasg1, float4* xq0) {
  int idx = blockIdx.x * 256 + threadIdx.x;
  int stride = gridDim.x * 256;
  for (int i = idx; i < 6 * NH; i += stride) state[i] = 0.0f;  // P0,P1,c0,c1
  for (int i = idx; i < 64 * 2 * 64; i += stride) {
    int j = i & 63, m = (i >> 6) & 1, k = i >> 7;
    const float* W = m ? liWh0 : gcWh0;
    Wg0[i] = make_float4(W[k * GG + j], W[k * GG + j + 64],
                         W[k * GG + j + 128], W[k * GG + j + 192]);
  }
  for (int i = idx; i < 64 * 4 * 64; i += stride) {
    int j = i & 63, m = (i >> 6) & 3, k = i >> 8;
    const float* W = (m == 0) ? gcWi1 : (m == 1) ? liWi1 : (m == 2) ? gcWh1 : liWh1;
    Wg1[i] = make_float4(W[k * GG + j], W[k * GG + j + 64],
                         W[k * GG + j + 128], W[k * GG + j + 192]);
  }
  if (idx < 64) {
    int j = idx;
    biasg0[j] = make_float4(
        gcbi0[j] + gcbh0[j] + libi0[j] + libh0[j],
        gcbi0[j + 64] + gcbh0[j + 64] + libi0[j + 64] + libh0[j + 64],
        gcbi0[j + 128] + gcbh0[j + 128] + libi0[j + 128] + libh0[j + 128],
        gcbi0[j + 192] + gcbh0[j + 192] + libi0[j + 192] + libh0[j + 192]);
    biasg1[j] = make_float4(
        gcbi1[j] + gcbh1[j] + libi1[j] + libh1[j],
        gcbi1[j + 64] + gcbh1[j + 64] + libi1[j + 64] + libh1[j + 64],
        gcbi1[j + 128] + gcbh1[j + 128] + libi1[j + 128] + libh1[j + 128],
        gcbi1[j + 192] + gcbh1[j + 192] + libi1[j + 192] + libh1[j + 192]);
  } else if (idx < 320) {
    int i = idx - 64;           // i = m*64 + j
    int j = i & 63, m = i >> 6; // m: 0,1 -> gcWi0 row 0/1; 2,3 -> liWi0 row 0/1
    const float* W = (m < 2) ? gcWi0 : liWi0;
    int kk = m & 1;
    xq0[i] = make_float4(W[kk * GG + j], W[kk * GG + j + 64],
                         W[kk * GG + j + 128], W[kk * GG + j + 192]);
  }
}

// ---------------------------------------------------------------------------
// Single adj pass: raw ELL (incl. +I diag) + dinv. Zero-fills ALL CAP slots
// (re-poison semantics: padding must be (col=0, val=0)). cnt padded to x8.
// ---------------------------------------------------------------------------
__launch_bounds__(256)
__global__ void k_build(const float* adj, float* dinv,
                        int* ell_col, float* ell_val, int* ell_cnt) {
  int r = blockIdx.x;
  __shared__ int cnt;
  __shared__ float red[256];
  if (threadIdx.x == 0) cnt = 0;
  __syncthreads();
  const float* row = adj + (size_t)r * NN;
  float s = 0.0f;
  for (int c = threadIdx.x; c < NN; c += 256) {
    float a = row[c];
    if (c == r) a += 1.0f;   // A = adj + I
    s += a;
    if (a != 0.0f) {
      int pos = atomicAdd(&cnt, 1);
      if (pos < CAP) {
        ell_col[(size_t)r * CAP + pos] = c;
        ell_val[(size_t)r * CAP + pos] = a;
      }
    }
  }
  red[threadIdx.x] = s;
  __syncthreads();
  for (int st = 128; st > 0; st >>= 1) {
    if (threadIdx.x < st) red[threadIdx.x] += red[threadIdx.x + st];
    __syncthreads();
  }
  int n = cnt < CAP ? cnt : CAP;
  for (int j = n + (int)threadIdx.x; j < CAP; j += 256) {
    ell_col[(size_t)r * CAP + j] = 0;
    ell_val[(size_t)r * CAP + j] = 0.0f;
  }
  if (threadIdx.x == 0) {
    int npad = (n + 7) & ~7;
    if (npad > CAP) npad = CAP;
    ell_cnt[r] = npad;
    dinv[r] = 1.0f / sqrtf(red[0]);  // rowsum + 1 >= 1
  }
}

__launch_bounds__(256)
__global__ void k_scale(const float* dinv, const int* ell_col, float* ell_val) {
  int idx = blockIdx.x * 256 + threadIdx.x;  // over NN*CAP
  int r = idx / CAP;
  if (r >= NN) return;
  float v = ell_val[idx];
  if (v != 0.0f) ell_val[idx] = v * dinv[r] * dinv[ell_col[idx]];
}

// ---------------------------------------------------------------------------
// Precompute gax[t][r][c] = (A @ x_t)[r][c]. Block = (t, 512-row segment).
// ---------------------------------------------------------------------------
__launch_bounds__(256)
__global__ void k_gax(const float* x, const int* ell_col, const float* ell_val,
                      const int* ell_cnt, float* gax) {
  int t = blockIdx.x >> 3;
  int seg = blockIdx.x & 7;
  __shared__ float xs[NN * 2];
  const float* xt = x + (size_t)t * NN * 2;
  for (int i = threadIdx.x; i < NN * 2; i += 256) xs[i] = xt[i];
  __syncthreads();
  int base = seg * 512 * 2;
  for (int oo = threadIdx.x; oo < 512 * 2; oo += 256) {
    int o = base + oo;
    int r = o >> 1, cmp = o & 1;
    int cnt = ell_cnt[r];
    const int* cp = ell_col + (size_t)r * CAP;
    const float* vp = ell_val + (size_t)r * CAP;
    float acc = 0.0f;
    for (int j = 0; j < cnt; j += 4) {
      acc += vp[j]     * xs[cp[j]     * 2 + cmp];
      acc += vp[j + 1] * xs[cp[j + 1] * 2 + cmp];
      acc += vp[j + 2] * xs[cp[j + 2] * 2 + cmp];
      acc += vp[j + 3] * xs[cp[j + 3] * 2 + cmp];
    }
    gax[(size_t)t * NN * 2 + o] = acc;
  }
}

// ---------------------------------------------------------------------------
// Cell 0 body (one block of 8 rows, 4 waves x 2 rows): gather from global
// (R0-identical); dense loop reads weights from ping-pong LDS fed by
// global_load_lds DMA. Chunk = 8 k's = 1024 float4 = 16 KB; 8 chunks;
// 1 barrier per chunk. Wave w stages its quarter (4 x 1 KB DMA calls).
// ---------------------------------------------------------------------------
__device__ __forceinline__ void cell0_body(
    int blk, int tid,
    const int* __restrict__ ell_col, const float* __restrict__ ell_val,
    const int* __restrict__ ell_cnt,
    const float2* __restrict__ Pr, float* __restrict__ Pw,
    float* __restrict__ c0,
    const float* __restrict__ xt, const float* __restrict__ gaxt,
    const float4* __restrict__ Wg0, const float4* __restrict__ biasg0,
    const float4* __restrict__ xq0, float4* wbuf) {
  const int wave = tid >> 6, lane = tid & 63;
  const int r0 = blk * 8 + wave * 2;

  // issue chunk-0 DMA now; completes (in vmcnt order) under the gather
  {
    const float4* src = Wg0 + wave * 256 + lane;
    float4* dst = wbuf + wave * 256;
#pragma unroll
    for (int i = 0; i < 4; i++) stage1k(src + i * 64, dst + i * 64);
  }

  int myc[2][3]; float myv[2][3]; int cnts[2];
#pragma unroll
  for (int rr = 0; rr < 2; rr++) {
    int r = r0 + rr;
    cnts[rr] = ell_cnt[r];
#pragma unroll
    for (int chk = 0; chk < 3; chk++) {
      myc[rr][chk] = ell_col[(size_t)r * CAP + chk * 64 + lane];
      myv[rr][chk] = ell_val[(size_t)r * CAP + chk * 64 + lane];
    }
  }
  float gacc[2], hl[2];
#pragma unroll
  for (int rr = 0; rr < 2; rr++) {
    int cnt = cnts[rr];
    float acc = 0.0f;
#pragma unroll
    for (int chk = 0; chk < 3; chk++) {
      int base = chk * 64;
      if (base < cnt) {
        int lim = cnt - base; if (lim > 64) lim = 64;  // multiple of 8
        int mc = myc[rr][chk]; float mv = myv[rr][chk];
        for (int m = 0; m < lim; m += 8) {
          float2 ld[8]; float vv[8];
#pragma unroll
          for (int i = 0; i < 8; i++) {
            int cc = bcast_i(mc, m + i);
            vv[i] = bcast_f(mv, m + i);
            ld[i] = Pr[(size_t)cc * 64 + lane];
          }
#pragma unroll
          for (int i = 0; i < 8; i++) acc += vv[i] * ld[i].x;
        }
      }
    }
    gacc[rr] = acc;
    hl[rr] = Pr[(size_t)(r0 + rr) * 64 + lane].x;
  }

  float4 acc[2];
  {
    float4 b = biasg0[lane];
    float4 qg0 = xq0[lane], qg1 = xq0[64 + lane];
    float4 ql0 = xq0[128 + lane], ql1 = xq0[192 + lane];
#pragma unroll
    for (int rr = 0; rr < 2; rr++) {
      float xx0 = xt[(size_t)(r0 + rr) * 2];
      float xx1 = xt[(size_t)(r0 + rr) * 2 + 1];
      float gg0 = gaxt[(size_t)(r0 + rr) * 2];
      float gg1 = gaxt[(size_t)(r0 + rr) * 2 + 1];
      acc[rr].x = b.x + gg0 * qg0.x + gg1 * qg1.x + xx0 * ql0.x + xx1 * ql1.x;
      acc[rr].y = b.y + gg0 * qg0.y + gg1 * qg1.y + xx0 * ql0.y + xx1 * ql1.y;
      acc[rr].z = b.z + gg0 * qg0.z + gg1 * qg1.z + xx0 * ql0.z + xx1 * ql1.z;
      acc[rr].w = b.w + gg0 * qg0.w + gg1 * qg1.w + xx0 * ql0.w + xx1 * ql1.w;
    }
  }

  __syncthreads();  // chunk-0 DMA drained (vmcnt 0) + all waves ready
  int cur = 0;
  for (int ch = 0; ch < 8; ch++) {
    if (ch + 1 < 8) {  // issue next-chunk DMA into the other buffer
      const float4* src = Wg0 + (ch + 1) * 1024 + wave * 256 + lane;
      float4* dst = wbuf + ((cur ^ 1) << 10) + wave * 256;
#pragma unroll
      for (int i = 0; i < 4; i++) stage1k(src + i * 64, dst + i * 64);
    }
    const float4* wb = wbuf + (cur << 10);
#pragma unroll
    for (int kk = 0; kk < 8; kk++) {
      int k = ch * 8 + kk;
      float4 w0 = wb[(kk * 2 + 0) * 64 + lane];
      float4 w1 = wb[(kk * 2 + 1) * 64 + lane];
#pragma unroll
      for (int rr = 0; rr < 2; rr++) {
        float a0 = bcast_f(gacc[rr], k);
        float a1 = bcast_f(hl[rr], k);
        acc[rr].x += a0 * w0.x + a1 * w1.x;
        acc[rr].y += a0 * w0.y + a1 * w1.y;
        acc[rr].z += a0 * w0.z + a1 * w1.z;
        acc[rr].w += a0 * w0.w + a1 * w1.w;
      }
    }
    __syncthreads();  // my DMA landed + all waves done reading buf[cur]
    cur ^= 1;
  }

#pragma unroll
  for (int rr = 0; rr < 2; rr++) {
    size_t gi = (size_t)(r0 + rr) * HH + lane;
    float cprev = c0[gi];
    float si = 1.0f / (1.0f + __expf(-acc[rr].x));
    float sf = 1.0f / (1.0f + __expf(-acc[rr].y));
    float so = 1.0f / (1.0f + __expf(-acc[rr].z));
    float cn = sf * cprev + si * tanhf(acc[rr].w);
    float hn = so * tanhf(cn);
    c0[gi] = cn;
    Pw[gi * 2 + 0] = hn;
  }
}

// ---------------------------------------------------------------------------
// Cell 1 body (one block of 8 rows): dual gather from paired {h0n,h1old};
// dense loop from ping-pong LDS. Chunk = 4 k's = 16 KB; 16 chunks.
// ---------------------------------------------------------------------------
__device__ __forceinline__ void cell1_body(
    int blk, int tid,
    const int* __restrict__ ell_col, const float* __restrict__ ell_val,
    const int* __restrict__ ell_cnt,
    const float2* __restrict__ Pr, float* __restrict__ Pw,
    float* __restrict__ c1,
    const float4* __restrict__ Wg1, const float4* __restrict__ biasg1,
    float4* wbuf) {
  const int wave = tid >> 6, lane = tid & 63;
  const int r0 = blk * 8 + wave * 2;

  // issue chunk-0 DMA now
  {
    const float4* src = Wg1 + wave * 256 + lane;
    float4* dst = wbuf + wave * 256;
#pragma unroll
    for (int i = 0; i < 4; i++) stage1k(src + i * 64, dst + i * 64);
  }

  int myc[2][3]; float myv[2][3]; int cnts[2];
#pragma unroll
  for (int rr = 0; rr < 2; rr++) {
    int r = r0 + rr;
    cnts[rr] = ell_cnt[r];
#pragma unroll
    for (int chk = 0; chk < 3; chk++) {
      myc[rr][chk] = ell_col[(size_t)r * CAP + chk * 64 + lane];
      myv[rr][chk] = ell_val[(size_t)r * CAP + chk * 64 + lane];
    }
  }
  float ga0[2], ga1[2], hl0[2], hl1[2];
#pragma unroll
  for (int rr = 0; rr < 2; rr++) {
    int cnt = cnts[rr];
    float a0 = 0.0f, a1 = 0.0f;
#pragma unroll
    for (int chk = 0; chk < 3; chk++) {
      int base = chk * 64;
      if (base < cnt) {
        int lim = cnt - base; if (lim > 64) lim = 64;  // multiple of 8
        int mc = myc[rr][chk]; float mv = myv[rr][chk];
        for (int m = 0; m < lim; m += 8) {
          float2 ld[8]; float vv[8];
#pragma unroll
          for (int i = 0; i < 8; i++) {
            int cc = bcast_i(mc, m + i);
            vv[i] = bcast_f(mv, m + i);
            ld[i] = Pr[(size_t)cc * 64 + lane];
          }
#pragma unroll
          for (int i = 0; i < 8; i++) {
            a0 += vv[i] * ld[i].x;
            a1 += vv[i] * ld[i].y;
          }
        }
      }
    }
    ga0[rr] = a0;
    ga1[rr] = a1;
    float2 hh = Pr[(size_t)(r0 + rr) * 64 + lane];
    hl0[rr] = hh.x;
    hl1[rr] = hh.y;
  }

  float4 acc[2];
  {
    float4 b = biasg1[lane];
    acc[0] = b; acc[1] = b;
  }

  __syncthreads();  // chunk-0 DMA drained + all waves ready
  int cur = 0;
  for (int ch = 0; ch < 16; ch++) {
    if (ch + 1 < 16) {
      const float4* src = Wg1 + (ch + 1) * 1024 + wave * 256 + lane;
      float4* dst = wbuf + ((cur ^ 1) << 10) + wave * 256;
#pragma unroll
      for (int i = 0; i < 4; i++) stage1k(src + i * 64, dst + i * 64);
    }
    const float4* wb = wbuf + (cur << 10);
#pragma unroll
    for (int kk = 0; kk < 4; kk++) {
      int k = ch * 4 + kk;
      float4 w0 = wb[(kk * 4 + 0) * 64 + lane];
      float4 w1 = wb[(kk * 4 + 1) * 64 + lane];
      float4 w2 = wb[(kk * 4 + 2) * 64 + lane];
      float4 w3 = wb[(kk * 4 + 3) * 64 + lane];
#pragma unroll
      for (int rr = 0; rr < 2; rr++) {
        float a0 = bcast_f(ga0[rr], k);   // (A@h0n)   -> gcWi1
        float a1 = bcast_f(hl0[rr], k);   // h0n       -> liWi1
        float a2 = bcast_f(ga1[rr], k);   // (A@h1old) -> gcWh1
        float a3 = bcast_f(hl1[rr], k);   // h1old     -> liWh1
        acc[rr].x += a0 * w0.x + a1 * w1.x + a2 * w2.x + a3 * w3.x;
        acc[rr].y += a0 * w0.y + a1 * w1.y + a2 * w2.y + a3 * w3.y;
        acc[rr].z += a0 * w0.z + a1 * w1.z + a2 * w2.z + a3 * w3.z;
        acc[rr].w += a0 * w0.w + a1 * w1.w + a2 * w2.w + a3 * w3.w;
      }
    }
    __syncthreads();  // my DMA landed + all waves done reading buf[cur]
    cur ^= 1;
  }

#pragma unroll
  for (int rr = 0; rr < 2; rr++) {
    size_t gi = (size_t)(r0 + rr) * HH + lane;
    float cprev = c1[gi];
    float si = 1.0f / (1.0f + __expf(-acc[rr].x));
    float sf = 1.0f / (1.0f + __expf(-acc[rr].y));
    float so = 1.0f / (1.0f + __expf(-acc[rr].z));
    float cn = sf * cprev + si * tanhf(acc[rr].w);
    float hn = so * tanhf(cn);
    c1[gi] = cn;
    Pw[gi * 2 + 1] = hn;
  }
}

// ---------------------------------------------------------------------------
// Fused step kernel: blocks [0, c0blocks) run cell0(t); the rest run
// cell1(t-1). Branch is block-uniform -> no barrier divergence.
// 256 threads, 2 x 16 KB LDS ping-pong -> 4 blocks/CU (16 waves/CU).
// ---------------------------------------------------------------------------
__launch_bounds__(256)
__global__ void k_cells(int c0blocks,
                        const int* __restrict__ ell_col,
                        const float* __restrict__ ell_val,
                        const int* __restrict__ ell_cnt,
                        const float2* __restrict__ Pr, float* __restrict__ Pw,
                        float* __restrict__ c0, float* __restrict__ c1,
                        const float* __restrict__ xt, const float* __restrict__ gaxt,
                        const float4* __restrict__ Wg0,
                        const float4* __restrict__ biasg0,
                        const float4* __restrict__ xq0,
                        const float4* __restrict__ Wg1,
                        const float4* __restrict__ biasg1) {
  __shared__ float4 wbuf[2048];  // 2 x 16 KB ping-pong
  int b = blockIdx.x;
  if (b < c0blocks) {
    cell0_body(b, threadIdx.x, ell_col, ell_val, ell_cnt, Pr, Pw, c0, xt, gaxt,
               Wg0, biasg0, xq0, wbuf);
  } else {
    cell1_body(b - c0blocks, threadIdx.x, ell_col, ell_val, ell_cnt, Pr, Pw, c1,
               Wg1, biasg1, wbuf);
  }
}

// ---------------------------------------------------------------------------
// Output projection: out[r,p] = h1[r,:] @ outW[:,p] + outb[p].
// h1 final = P0[..][1] (launch 48 writes P[0].y).
// ---------------------------------------------------------------------------
__launch_bounds__(256)
__global__ void k_out(const float* __restrict__ P0, const float* __restrict__ outW,
                      const float* __restrict__ outb, float* __restrict__ out) {
  int idx = blockIdx.x * 256 + threadIdx.x;
  if (idx >= NN * PP) return;
  int r = idx / PP, p = idx - r * PP;
  float acc = outb[p];
  const float* hrow = P0 + (size_t)r * 128;
#pragma unroll 16
  for (int k = 0; k < HH; k++) acc += hrow[k * 2 + 1] * outW[k * PP + p];
  out[idx] = acc;
}

extern "C" void kernel_launch(void* const* d_in, const int* in_sizes, int n_in,
                              void* d_out, int out_size, void* d_ws, size_t ws_size,
                              hipStream_t stream) {
  const float* x     = (const float*)d_in[0];
  const float* adj   = (const float*)d_in[1];
  const float* gcWi0 = (const float*)d_in[2];
  const float* gcbi0 = (const float*)d_in[3];
  const float* gcWh0 = (const float*)d_in[4];
  const float* gcbh0 = (const float*)d_in[5];
  const float* liWi0 = (const float*)d_in[6];
  const float* libi0 = (const float*)d_in[7];
  const float* liWh0 = (const float*)d_in[8];
  const float* libh0 = (const float*)d_in[9];
  const float* gcWi1 = (const float*)d_in[10];
  const float* gcbi1 = (const float*)d_in[11];
  const float* gcWh1 = (const float*)d_in[12];
  const float* gcbh1 = (const float*)d_in[13];
  const float* liWi1 = (const float*)d_in[14];
  const float* libi1 = (const float*)d_in[15];
  const float* liWh1 = (const float*)d_in[16];
  const float* libh1 = (const float*)d_in[17];
  const float* outW  = (const float*)d_in[18];
  const float* outb  = (const float*)d_in[19];

  char* ws = (char*)d_ws;
  size_t off = 0;
  auto carve = [&](size_t bytes) {
    void* p = ws + off;
    off += (bytes + 255) & ~(size_t)255;
    return p;
  };
  float*  dinv    = (float*)carve((size_t)NN * 4);
  int*    ell_col = (int*)carve((size_t)NN * CAP * 4);
  float*  ell_val = (float*)carve((size_t)NN * CAP * 4);
  int*    ell_cnt = (int*)carve((size_t)NN * 4);
  float*  state   = (float*)carve((size_t)6 * NH * 4);  // P0,P1 (2NH each), c0, c1
  float*  gax     = (float*)carve((size_t)TT * NN * 2 * 4);
  float4* Wg0     = (float4*)carve((size_t)64 * 2 * 64 * 16);
  float4* Wg1     = (float4*)carve((size_t)64 * 4 * 64 * 16);
  float4* biasg0  = (float4*)carve((size_t)64 * 16);
  float4* biasg1  = (float4*)carve((size_t)64 * 16);
  float4* xq0     = (float4*)carve((size_t)256 * 16);

  float* P[2] = {state, state + 2 * NH};
  float* c0 = state + 4 * NH;
  float* c1 = state + 5 * NH;

  k_prep<<<512, 256, 0, stream>>>(gcbi0, gcbh0, libi0, libh0,
                                  gcbi1, gcbh1, libi1, libh1,
                                  gcWh0, liWh0, gcWi1, liWi1, gcWh1, liWh1,
                                  gcWi0, liWi0,
                                  state, Wg0, Wg1, biasg0, biasg1, xq0);
  k_build<<<NN, 256, 0, stream>>>(adj, dinv, ell_col, ell_val, ell_cnt);
  k_scale<<<(NN * CAP) / 256, 256, 0, stream>>>(dinv, ell_col, ell_val);
  k_gax<<<TT * 8, 256, 0, stream>>>(x, ell_col, ell_val, ell_cnt, gax);

  // Software-pipelined step loop: launch k runs {cell0(k) || cell1(k-1)}.
  // Launch k reads P[(k&1)^1], writes P[k&1].
  for (int k = 0; k <= TT; k++) {
    int A = k & 1;
    int c0blocks = (k < TT) ? NN / 8 : 0;          // cell0 active for k<48
    int c1blocks = (k > 0) ? NN / 8 : 0;           // cell1 active for k>0
    int grid = c0blocks + c1blocks;
    int tx = (k < TT) ? k : (TT - 1);              // xt/gaxt unused when k==TT
    k_cells<<<grid, 256, 0, stream>>>(
        c0blocks, ell_col, ell_val, ell_cnt,
        (const float2*)P[A ^ 1], P[A], c0, c1,
        x + (size_t)tx * NN * 2, gax + (size_t)tx * NN * 2,
        Wg0, biasg0, xq0, Wg1, biasg1);
  }

  // Launch 48 (A=0) wrote h1(47) into P[0].y
  k_out<<<(NN * PP + 255) / 256, 256, 0, stream>>>(P[0], outW, outb, (float*)d_out);
}

// Round 7
// 1879.502 us; speedup vs baseline: 4.0905x; 2.5851x over previous
//
#include <hip/hip_runtime.h>
#include <math.h>

// Problem constants
#define NN 4096
#define TT 48
#define HH 64
#define GG 256   // 4*H
#define PP 12
#define CAP 192  // ELL slots per row, 3 x 64 -> whole-wave chunk loads, no guard
#define NH (NN * HH)

// readlane broadcast: uniform lane index -> SGPR broadcast, off the LDS pipe
__device__ __forceinline__ float bcast_f(float v, int lane) {
  return __int_as_float(__builtin_amdgcn_readlane(__float_as_int(v), lane));
}
__device__ __forceinline__ int bcast_i(int v, int lane) {
  return __builtin_amdgcn_readlane(v, lane);
}

// ---------------------------------------------------------------------------
// h-state: paired buffers P[2], each [N][64][2]: {h0, h1} interleaved.
// Launch k (k=0..48) computes cell0(t=k) [k<48] and cell1(s=k-1) [k>0]:
//   READS only P[(k&1)^1]  (cell0: .x = h0(k-1); cell1: {h0(k-1), h1(k-2)})
//   WRITES only P[k&1]     (cell0 -> .x = h0(k);  cell1 -> .y = h1(k-1))
// Different 4B slots of the same float2 -> no intra-launch hazard; one fused
// launch per step. Final h1(47) in P[0].y.
//
// R6: R0 structure (1024 blocks x 4 waves x 2 rows, 16 waves/CU) + ping-pong
// LDS weight staging via REGISTER loads, ch-loop pinned to unroll 1.
// History:
//   R0 48.5us: weights re-streamed per wave (768 MB/launch L2 ~28us) poorly
//              overlapped with ~20us VALU (46% VALUBusy).
//   R1 59us:   occupancy push -> forced VGPR 32, spills. TLP not the lever.
//   R2 66.5us: bytes/4 via 8 rows/wave but 1 wave/SIMD -> latency exposed.
//   R3 61.4us: single-buffered LDS staging -> transfer between barriers,
//              serialized (VGPR 72, no spill -- staging per se is fine).
//   R4 164us / R5 105us: double-buffered (reg / global_load_lds) -> VGPR
//              256 + 35-75 MB/launch scratch: compiler FULLY UNROLLS the
//              constant-trip ch-loop and hoists all iterations' prefetch
//              (Wg is restrict-const, no alias -> legal) above the
//              barriers: 15 iter x 16 VGPR staging = explosion.
// Fix: #pragma unroll 1 on the ch loops (single prefetch copy in body;
// hoisting across the back-edge barrier = software pipelining LLVM won't
// do here) + loop-carried prefetch pointer. Live staging = 4 float4 =
// 16 VGPR. Weight L2 bytes /4 (768 -> 192 MB/launch). 2 x 16 KB chunks =
// 32 KB LDS -> 4 blocks/CU (16 waves/CU, R0's proven TLP point). FP order
// per row identical to R0.
//
// GATE-QUAD mapping: lane j owns cols {j, j+64, j+128, j+192} = (i,f,o,g) of
// hidden unit j. One wave = 2 rows x 256 cols; full quad in one lane's
// float4 acc.
//   Wg0[(k*2+m)*64+j] = float4 gate-quad, m in {gcWh0, liWh0}
//   Wg1[(k*4+m)*64+j] = float4 gate-quad, m in {gcWi1, liWi1, gcWh1, liWh1}
// ---------------------------------------------------------------------------
__launch_bounds__(256)
__global__ void k_prep(const float* gcbi0, const float* gcbh0,
                       const float* libi0, const float* libh0,
                       const float* gcbi1, const float* gcbh1,
                       const float* libi1, const float* libh1,
                       const float* gcWh0, const float* liWh0,
                       const float* gcWi1, const float* liWi1,
                       const float* gcWh1, const float* liWh1,
                       const float* gcWi0, const float* liWi0,
                       float* state, float4* Wg0, float4* Wg1,
                       float4* biasg0, float4* biasg1, float4* xq0) {
  int idx = blockIdx.x * 256 + threadIdx.x;
  int stride = gridDim.x * 256;
  for (int i = idx; i < 6 * NH; i += stride) state[i] = 0.0f;  // P0,P1,c0,c1
  for (int i = idx; i < 64 * 2 * 64; i += stride) {
    int j = i & 63, m = (i >> 6) & 1, k = i >> 7;
    const float* W = m ? liWh0 : gcWh0;
    Wg0[i] = make_float4(W[k * GG + j], W[k * GG + j + 64],
                         W[k * GG + j + 128], W[k * GG + j + 192]);
  }
  for (int i = idx; i < 64 * 4 * 64; i += stride) {
    int j = i & 63, m = (i >> 6) & 3, k = i >> 8;
    const float* W = (m == 0) ? gcWi1 : (m == 1) ? liWi1 : (m == 2) ? gcWh1 : liWh1;
    Wg1[i] = make_float4(W[k * GG + j], W[k * GG + j + 64],
                         W[k * GG + j + 128], W[k * GG + j + 192]);
  }
  if (idx < 64) {
    int j = idx;
    biasg0[j] = make_float4(
        gcbi0[j] + gcbh0[j] + libi0[j] + libh0[j],
        gcbi0[j + 64] + gcbh0[j + 64] + libi0[j + 64] + libh0[j + 64],
        gcbi0[j + 128] + gcbh0[j + 128] + libi0[j + 128] + libh0[j + 128],
        gcbi0[j + 192] + gcbh0[j + 192] + libi0[j + 192] + libh0[j + 192]);
    biasg1[j] = make_float4(
        gcbi1[j] + gcbh1[j] + libi1[j] + libh1[j],
        gcbi1[j + 64] + gcbh1[j + 64] + libi1[j + 64] + libh1[j + 64],
        gcbi1[j + 128] + gcbh1[j + 128] + libi1[j + 128] + libh1[j + 128],
        gcbi1[j + 192] + gcbh1[j + 192] + libi1[j + 192] + libh1[j + 192]);
  } else if (idx < 320) {
    int i = idx - 64;           // i = m*64 + j
    int j = i & 63, m = i >> 6; // m: 0,1 -> gcWi0 row 0/1; 2,3 -> liWi0 row 0/1
    const float* W = (m < 2) ? gcWi0 : liWi0;
    int kk = m & 1;
    xq0[i] = make_float4(W[kk * GG + j], W[kk * GG + j + 64],
                         W[kk * GG + j + 128], W[kk * GG + j + 192]);
  }
}

// ---------------------------------------------------------------------------
// Single adj pass: raw ELL (incl. +I diag) + dinv. Zero-fills ALL CAP slots
// (re-poison semantics: padding must be (col=0, val=0)). cnt padded to x8.
// ---------------------------------------------------------------------------
__launch_bounds__(256)
__global__ void k_build(const float* adj, float* dinv,
                        int* ell_col, float* ell_val, int* ell_cnt) {
  int r = blockIdx.x;
  __shared__ int cnt;
  __shared__ float red[256];
  if (threadIdx.x == 0) cnt = 0;
  __syncthreads();
  const float* row = adj + (size_t)r * NN;
  float s = 0.0f;
  for (int c = threadIdx.x; c < NN; c += 256) {
    float a = row[c];
    if (c == r) a += 1.0f;   // A = adj + I
    s += a;
    if (a != 0.0f) {
      int pos = atomicAdd(&cnt, 1);
      if (pos < CAP) {
        ell_col[(size_t)r * CAP + pos] = c;
        ell_val[(size_t)r * CAP + pos] = a;
      }
    }
  }
  red[threadIdx.x] = s;
  __syncthreads();
  for (int st = 128; st > 0; st >>= 1) {
    if (threadIdx.x < st) red[threadIdx.x] += red[threadIdx.x + st];
    __syncthreads();
  }
  int n = cnt < CAP ? cnt : CAP;
  for (int j = n + (int)threadIdx.x; j < CAP; j += 256) {
    ell_col[(size_t)r * CAP + j] = 0;
    ell_val[(size_t)r * CAP + j] = 0.0f;
  }
  if (threadIdx.x == 0) {
    int npad = (n + 7) & ~7;
    if (npad > CAP) npad = CAP;
    ell_cnt[r] = npad;
    dinv[r] = 1.0f / sqrtf(red[0]);  // rowsum + 1 >= 1
  }
}

__launch_bounds__(256)
__global__ void k_scale(const float* dinv, const int* ell_col, float* ell_val) {
  int idx = blockIdx.x * 256 + threadIdx.x;  // over NN*CAP
  int r = idx / CAP;
  if (r >= NN) return;
  float v = ell_val[idx];
  if (v != 0.0f) ell_val[idx] = v * dinv[r] * dinv[ell_col[idx]];
}

// ---------------------------------------------------------------------------
// Precompute gax[t][r][c] = (A @ x_t)[r][c]. Block = (t, 512-row segment).
// ---------------------------------------------------------------------------
__launch_bounds__(256)
__global__ void k_gax(const float* x, const int* ell_col, const float* ell_val,
                      const int* ell_cnt, float* gax) {
  int t = blockIdx.x >> 3;
  int seg = blockIdx.x & 7;
  __shared__ float xs[NN * 2];
  const float* xt = x + (size_t)t * NN * 2;
  for (int i = threadIdx.x; i < NN * 2; i += 256) xs[i] = xt[i];
  __syncthreads();
  int base = seg * 512 * 2;
  for (int oo = threadIdx.x; oo < 512 * 2; oo += 256) {
    int o = base + oo;
    int r = o >> 1, cmp = o & 1;
    int cnt = ell_cnt[r];
    const int* cp = ell_col + (size_t)r * CAP;
    const float* vp = ell_val + (size_t)r * CAP;
    float acc = 0.0f;
    for (int j = 0; j < cnt; j += 4) {
      acc += vp[j]     * xs[cp[j]     * 2 + cmp];
      acc += vp[j + 1] * xs[cp[j + 1] * 2 + cmp];
      acc += vp[j + 2] * xs[cp[j + 2] * 2 + cmp];
      acc += vp[j + 3] * xs[cp[j + 3] * 2 + cmp];
    }
    gax[(size_t)t * NN * 2 + o] = acc;
  }
}

// ---------------------------------------------------------------------------
// Cell 0 body (one block of 8 rows, 4 waves x 2 rows): gather from global
// (R0-identical); dense loop reads weights from ping-pong LDS. Chunk =
// 8 k's = 1024 float4 = 16 KB; 8 chunks; 1 barrier per chunk. ch-loop is
// unroll-1 so only ONE prefetch copy (4 float4 = 16 VGPR) is ever live.
// ---------------------------------------------------------------------------
__device__ __forceinline__ void cell0_body(
    int blk, int tid,
    const int* __restrict__ ell_col, const float* __restrict__ ell_val,
    const int* __restrict__ ell_cnt,
    const float2* __restrict__ Pr, float* __restrict__ Pw,
    float* __restrict__ c0,
    const float* __restrict__ xt, const float* __restrict__ gaxt,
    const float4* __restrict__ Wg0, const float4* __restrict__ biasg0,
    const float4* __restrict__ xq0, float4* wbuf) {
  const int wave = tid >> 6, lane = tid & 63;
  const int r0 = blk * 8 + wave * 2;

  // issue chunk-0 loads NOW; they complete during the gather phase
  const float4* pf = Wg0 + tid;
  float4 st0 = pf[0], st1 = pf[256], st2 = pf[512], st3 = pf[768];
  pf += 1024;

  int myc[2][3]; float myv[2][3]; int cnts[2];
#pragma unroll
  for (int rr = 0; rr < 2; rr++) {
    int r = r0 + rr;
    cnts[rr] = ell_cnt[r];
#pragma unroll
    for (int chk = 0; chk < 3; chk++) {
      myc[rr][chk] = ell_col[(size_t)r * CAP + chk * 64 + lane];
      myv[rr][chk] = ell_val[(size_t)r * CAP + chk * 64 + lane];
    }
  }
  float gacc[2], hl[2];
#pragma unroll
  for (int rr = 0; rr < 2; rr++) {
    int cnt = cnts[rr];
    float acc = 0.0f;
#pragma unroll
    for (int chk = 0; chk < 3; chk++) {
      int base = chk * 64;
      if (base < cnt) {
        int lim = cnt - base; if (lim > 64) lim = 64;  // multiple of 8
        int mc = myc[rr][chk]; float mv = myv[rr][chk];
        for (int m = 0; m < lim; m += 8) {
          float2 ld[8]; float vv[8];
#pragma unroll
          for (int i = 0; i < 8; i++) {
            int cc = bcast_i(mc, m + i);
            vv[i] = bcast_f(mv, m + i);
            ld[i] = Pr[(size_t)cc * 64 + lane];
          }
#pragma unroll
          for (int i = 0; i < 8; i++) acc += vv[i] * ld[i].x;
        }
      }
    }
    gacc[rr] = acc;
    hl[rr] = Pr[(size_t)(r0 + rr) * 64 + lane].x;
  }

  float4 acc[2];
  {
    float4 b = biasg0[lane];
    float4 qg0 = xq0[lane], qg1 = xq0[64 + lane];
    float4 ql0 = xq0[128 + lane], ql1 = xq0[192 + lane];
#pragma unroll
    for (int rr = 0; rr < 2; rr++) {
      float xx0 = xt[(size_t)(r0 + rr) * 2];
      float xx1 = xt[(size_t)(r0 + rr) * 2 + 1];
      float gg0 = gaxt[(size_t)(r0 + rr) * 2];
      float gg1 = gaxt[(size_t)(r0 + rr) * 2 + 1];
      acc[rr].x = b.x + gg0 * qg0.x + gg1 * qg1.x + xx0 * ql0.x + xx1 * ql1.x;
      acc[rr].y = b.y + gg0 * qg0.y + gg1 * qg1.y + xx0 * ql0.y + xx1 * ql1.y;
      acc[rr].z = b.z + gg0 * qg0.z + gg1 * qg1.z + xx0 * ql0.z + xx1 * ql1.z;
      acc[rr].w = b.w + gg0 * qg0.w + gg1 * qg1.w + xx0 * ql0.w + xx1 * ql1.w;
    }
  }

  // write chunk 0 and enter the ping-pong loop
  wbuf[tid] = st0; wbuf[256 + tid] = st1;
  wbuf[512 + tid] = st2; wbuf[768 + tid] = st3;
  __syncthreads();
  int cur = 0;
#pragma unroll 1
  for (int ch = 0; ch < 8; ch++) {
    if (ch + 1 < 8) {  // issue next-chunk loads; compute below covers latency
      st0 = pf[0]; st1 = pf[256]; st2 = pf[512]; st3 = pf[768];
      pf += 1024;
    }
    const float4* wb = wbuf + (cur << 10);
#pragma unroll
    for (int kk = 0; kk < 8; kk++) {
      int k = ch * 8 + kk;
      float4 w0 = wb[(kk * 2 + 0) * 64 + lane];
      float4 w1 = wb[(kk * 2 + 1) * 64 + lane];
#pragma unroll
      for (int rr = 0; rr < 2; rr++) {
        float a0 = bcast_f(gacc[rr], k);
        float a1 = bcast_f(hl[rr], k);
        acc[rr].x += a0 * w0.x + a1 * w1.x;
        acc[rr].y += a0 * w0.y + a1 * w1.y;
        acc[rr].z += a0 * w0.z + a1 * w1.z;
        acc[rr].w += a0 * w0.w + a1 * w1.w;
      }
    }
    if (ch + 1 < 8) {
      cur ^= 1;
      float4* dst = wbuf + (cur << 10) + tid;
      dst[0] = st0; dst[256] = st1; dst[512] = st2; dst[768] = st3;
      __syncthreads();  // writes visible; all waves past chunk ch
    }
  }

#pragma unroll
  for (int rr = 0; rr < 2; rr++) {
    size_t gi = (size_t)(r0 + rr) * HH + lane;
    float cprev = c0[gi];
    float si = 1.0f / (1.0f + __expf(-acc[rr].x));
    float sf = 1.0f / (1.0f + __expf(-acc[rr].y));
    float so = 1.0f / (1.0f + __expf(-acc[rr].z));
    float cn = sf * cprev + si * tanhf(acc[rr].w);
    float hn = so * tanhf(cn);
    c0[gi] = cn;
    Pw[gi * 2 + 0] = hn;
  }
}

// ---------------------------------------------------------------------------
// Cell 1 body (one block of 8 rows): dual gather from paired {h0n,h1old};
// dense loop from ping-pong LDS. Chunk = 4 k's = 16 KB; 16 chunks;
// ch-loop unroll-1 (see cell0 comment).
// ---------------------------------------------------------------------------
__device__ __forceinline__ void cell1_body(
    int blk, int tid,
    const int* __restrict__ ell_col, const float* __restrict__ ell_val,
    const int* __restrict__ ell_cnt,
    const float2* __restrict__ Pr, float* __restrict__ Pw,
    float* __restrict__ c1,
    const float4* __restrict__ Wg1, const float4* __restrict__ biasg1,
    float4* wbuf) {
  const int wave = tid >> 6, lane = tid & 63;
  const int r0 = blk * 8 + wave * 2;

  // issue chunk-0 loads NOW; they complete during the gather phase
  const float4* pf = Wg1 + tid;
  float4 st0 = pf[0], st1 = pf[256], st2 = pf[512], st3 = pf[768];
  pf += 1024;

  int myc[2][3]; float myv[2][3]; int cnts[2];
#pragma unroll
  for (int rr = 0; rr < 2; rr++) {
    int r = r0 + rr;
    cnts[rr] = ell_cnt[r];
#pragma unroll
    for (int chk = 0; chk < 3; chk++) {
      myc[rr][chk] = ell_col[(size_t)r * CAP + chk * 64 + lane];
      myv[rr][chk] = ell_val[(size_t)r * CAP + chk * 64 + lane];
    }
  }
  float ga0[2], ga1[2], hl0[2], hl1[2];
#pragma unroll
  for (int rr = 0; rr < 2; rr++) {
    int cnt = cnts[rr];
    float a0 = 0.0f, a1 = 0.0f;
#pragma unroll
    for (int chk = 0; chk < 3; chk++) {
      int base = chk * 64;
      if (base < cnt) {
        int lim = cnt - base; if (lim > 64) lim = 64;  // multiple of 8
        int mc = myc[rr][chk]; float mv = myv[rr][chk];
        for (int m = 0; m < lim; m += 8) {
          float2 ld[8]; float vv[8];
#pragma unroll
          for (int i = 0; i < 8; i++) {
            int cc = bcast_i(mc, m + i);
            vv[i] = bcast_f(mv, m + i);
            ld[i] = Pr[(size_t)cc * 64 + lane];
          }
#pragma unroll
          for (int i = 0; i < 8; i++) {
            a0 += vv[i] * ld[i].x;
            a1 += vv[i] * ld[i].y;
          }
        }
      }
    }
    ga0[rr] = a0;
    ga1[rr] = a1;
    float2 hh = Pr[(size_t)(r0 + rr) * 64 + lane];
    hl0[rr] = hh.x;
    hl1[rr] = hh.y;
  }

  float4 acc[2];
  {
    float4 b = biasg1[lane];
    acc[0] = b; acc[1] = b;
  }

  // write chunk 0 and enter the ping-pong loop
  wbuf[tid] = st0; wbuf[256 + tid] = st1;
  wbuf[512 + tid] = st2; wbuf[768 + tid] = st3;
  __syncthreads();
  int cur = 0;
#pragma unroll 1
  for (int ch = 0; ch < 16; ch++) {
    if (ch + 1 < 16) {
      st0 = pf[0]; st1 = pf[256]; st2 = pf[512]; st3 = pf[768];
      pf += 1024;
    }
    const float4* wb = wbuf + (cur << 10);
#pragma unroll
    for (int kk = 0; kk < 4; kk++) {
      int k = ch * 4 + kk;
      float4 w0 = wb[(kk * 4 + 0) * 64 + lane];
      float4 w1 = wb[(kk * 4 + 1) * 64 + lane];
      float4 w2 = wb[(kk * 4 + 2) * 64 + lane];
      float4 w3 = wb[(kk * 4 + 3) * 64 + lane];
#pragma unroll
      for (int rr = 0; rr < 2; rr++) {
        float a0 = bcast_f(ga0[rr], k);   // (A@h0n)   -> gcWi1
        float a1 = bcast_f(hl0[rr], k);   // h0n       -> liWi1
        float a2 = bcast_f(ga1[rr], k);   // (A@h1old) -> gcWh1
        float a3 = bcast_f(hl1[rr], k);   // h1old     -> liWh1
        acc[rr].x += a0 * w0.x + a1 * w1.x + a2 * w2.x + a3 * w3.x;
        acc[rr].y += a0 * w0.y + a1 * w1.y + a2 * w2.y + a3 * w3.y;
        acc[rr].z += a0 * w0.z + a1 * w1.z + a2 * w2.z + a3 * w3.z;
        acc[rr].w += a0 * w0.w + a1 * w1.w + a2 * w2.w + a3 * w3.w;
      }
    }
    if (ch + 1 < 16) {
      cur ^= 1;
      float4* dst = wbuf + (cur << 10) + tid;
      dst[0] = st0; dst[256] = st1; dst[512] = st2; dst[768] = st3;
      __syncthreads();  // writes visible; all waves past chunk ch
    }
  }

#pragma unroll
  for (int rr = 0; rr < 2; rr++) {
    size_t gi = (size_t)(r0 + rr) * HH + lane;
    float cprev = c1[gi];
    float si = 1.0f / (1.0f + __expf(-acc[rr].x));
    float sf = 1.0f / (1.0f + __expf(-acc[rr].y));
    float so = 1.0f / (1.0f + __expf(-acc[rr].z));
    float cn = sf * cprev + si * tanhf(acc[rr].w);
    float hn = so * tanhf(cn);
    c1[gi] = cn;
    Pw[gi * 2 + 1] = hn;
  }
}

// ---------------------------------------------------------------------------
// Fused step kernel: blocks [0, c0blocks) run cell0(t); the rest run
// cell1(t-1). Branch is block-uniform -> no barrier divergence.
// 256 threads, 2 x 16 KB LDS ping-pong -> 4 blocks/CU (16 waves/CU).
// ---------------------------------------------------------------------------
__launch_bounds__(256)
__global__ void k_cells(int c0blocks,
                        const int* __restrict__ ell_col,
                        const float* __restrict__ ell_val,
                        const int* __restrict__ ell_cnt,
                        const float2* __restrict__ Pr, float* __restrict__ Pw,
                        float* __restrict__ c0, float* __restrict__ c1,
                        const float* __restrict__ xt, const float* __restrict__ gaxt,
                        const float4* __restrict__ Wg0,
                        const float4* __restrict__ biasg0,
                        const float4* __restrict__ xq0,
                        const float4* __restrict__ Wg1,
                        const float4* __restrict__ biasg1) {
  __shared__ float4 wbuf[2048];  // 2 x 16 KB ping-pong
  int b = blockIdx.x;
  if (b < c0blocks) {
    cell0_body(b, threadIdx.x, ell_col, ell_val, ell_cnt, Pr, Pw, c0, xt, gaxt,
               Wg0, biasg0, xq0, wbuf);
  } else {
    cell1_body(b - c0blocks, threadIdx.x, ell_col, ell_val, ell_cnt, Pr, Pw, c1,
               Wg1, biasg1, wbuf);
  }
}

// ---------------------------------------------------------------------------
// Output projection: out[r,p] = h1[r,:] @ outW[:,p] + outb[p].
// h1 final = P0[..][1] (launch 48 writes P[0].y).
// ---------------------------------------------------------------------------
__launch_bounds__(256)
__global__ void k_out(const float* __restrict__ P0, const float* __restrict__ outW,
                      const float* __restrict__ outb, float* __restrict__ out) {
  int idx = blockIdx.x * 256 + threadIdx.x;
  if (idx >= NN * PP) return;
  int r = idx / PP, p = idx - r * PP;
  float acc = outb[p];
  const float* hrow = P0 + (size_t)r * 128;
#pragma unroll 16
  for (int k = 0; k < HH; k++) acc += hrow[k * 2 + 1] * outW[k * PP + p];
  out[idx] = acc;
}

extern "C" void kernel_launch(void* const* d_in, const int* in_sizes, int n_in,
                              void* d_out, int out_size, void* d_ws, size_t ws_size,
                              hipStream_t stream) {
  const float* x     = (const float*)d_in[0];
  const float* adj   = (const float*)d_in[1];
  const float* gcWi0 = (const float*)d_in[2];
  const float* gcbi0 = (const float*)d_in[3];
  const float* gcWh0 = (const float*)d_in[4];
  const float* gcbh0 = (const float*)d_in[5];
  const float* liWi0 = (const float*)d_in[6];
  const float* libi0 = (const float*)d_in[7];
  const float* liWh0 = (const float*)d_in[8];
  const float* libh0 = (const float*)d_in[9];
  const float* gcWi1 = (const float*)d_in[10];
  const float* gcbi1 = (const float*)d_in[11];
  const float* gcWh1 = (const float*)d_in[12];
  const float* gcbh1 = (const float*)d_in[13];
  const float* liWi1 = (const float*)d_in[14];
  const float* libi1 = (const float*)d_in[15];
  const float* liWh1 = (const float*)d_in[16];
  const float* libh1 = (const float*)d_in[17];
  const float* outW  = (const float*)d_in[18];
  const float* outb  = (const float*)d_in[19];

  char* ws = (char*)d_ws;
  size_t off = 0;
  auto carve = [&](size_t bytes) {
    void* p = ws + off;
    off += (bytes + 255) & ~(size_t)255;
    return p;
  };
  float*  dinv    = (float*)carve((size_t)NN * 4);
  int*    ell_col = (int*)carve((size_t)NN * CAP * 4);
  float*  ell_val = (float*)carve((size_t)NN * CAP * 4);
  int*    ell_cnt = (int*)carve((size_t)NN * 4);
  float*  state   = (float*)carve((size_t)6 * NH * 4);  // P0,P1 (2NH each), c0, c1
  float*  gax     = (float*)carve((size_t)TT * NN * 2 * 4);
  float4* Wg0     = (float4*)carve((size_t)64 * 2 * 64 * 16);
  float4* Wg1     = (float4*)carve((size_t)64 * 4 * 64 * 16);
  float4* biasg0  = (float4*)carve((size_t)64 * 16);
  float4* biasg1  = (float4*)carve((size_t)64 * 16);
  float4* xq0     = (float4*)carve((size_t)256 * 16);

  float* P[2] = {state, state + 2 * NH};
  float* c0 = state + 4 * NH;
  float* c1 = state + 5 * NH;

  k_prep<<<512, 256, 0, stream>>>(gcbi0, gcbh0, libi0, libh0,
                                  gcbi1, gcbh1, libi1, libh1,
                                  gcWh0, liWh0, gcWi1, liWi1, gcWh1, liWh1,
                                  gcWi0, liWi0,
                                  state, Wg0, Wg1, biasg0, biasg1, xq0);
  k_build<<<NN, 256, 0, stream>>>(adj, dinv, ell_col, ell_val, ell_cnt);
  k_scale<<<(NN * CAP) / 256, 256, 0, stream>>>(dinv, ell_col, ell_val);
  k_gax<<<TT * 8, 256, 0, stream>>>(x, ell_col, ell_val, ell_cnt, gax);

  // Software-pipelined step loop: launch k runs {cell0(k) || cell1(k-1)}.
  // Launch k reads P[(k&1)^1], writes P[k&1].
  for (int k = 0; k <= TT; k++) {
    int A = k & 1;
    int c0blocks = (k < TT) ? NN / 8 : 0;          // cell0 active for k<48
    int c1blocks = (k > 0) ? NN / 8 : 0;           // cell1 active for k>0
    int grid = c0blocks + c1blocks;
    int tx = (k < TT) ? k : (TT - 1);              // xt/gaxt unused when k==TT
    k_cells<<<grid, 256, 0, stream>>>(
        c0blocks, ell_col, ell_val, ell_cnt,
        (const float2*)P[A ^ 1], P[A], c0, c1,
        x + (size_t)tx * NN * 2, gax + (size_t)tx * NN * 2,
        Wg0, biasg0, xq0, Wg1, biasg1);
  }

  // Launch 48 (A=0) wrote h1(47) into P[0].y
  k_out<<<(NN * PP + 255) / 256, 256, 0, stream>>>(P[0], outW, outb, (float*)d_out);
}

// Round 8
// 1797.014 us; speedup vs baseline: 4.2783x; 1.0459x over previous
//
#include <hip/hip_runtime.h>
#include <math.h>

// Problem constants
#define NN 4096
#define TT 48
#define HH 64
#define GG 256   // 4*H
#define PP 12
#define CAP 192  // ELL slots per row, 3 x 64 -> whole-wave chunk loads, no guard
#define NH (NN * HH)

// readlane broadcast: uniform lane index -> SGPR broadcast, off the LDS pipe
__device__ __forceinline__ float bcast_f(float v, int lane) {
  return __int_as_float(__builtin_amdgcn_readlane(__float_as_int(v), lane));
}
__device__ __forceinline__ int bcast_i(int v, int lane) {
  return __builtin_amdgcn_readlane(v, lane);
}

// ---------------------------------------------------------------------------
// h-state: paired buffers P[2], each [N][64][2]: {h0, h1} interleaved.
// Launch k (k=0..48) computes cell0(t=k) [k<48] and cell1(s=k-1) [k>0]:
//   READS only P[(k&1)^1]  (cell0: .x = h0(k-1); cell1: {h0(k-1), h1(k-2)})
//   WRITES only P[k&1]     (cell0 -> .x = h0(k);  cell1 -> .y = h1(k-1))
// Final h1(47) in P[0].y.
//
// R7: MERGED ROLES. Key algebraic fact: at launch k, cell0's gather
// gacc = A@h0(k-1) (= A@Pr.x) and cell1's ga0 = A@inp = A@h0(k-1) are THE
// SAME VALUES -- R6 computed them twice in separate blocks (and read the
// 6.3 MB ELL twice: FETCH_SIZE 14 MB ~ 2x ELL). One block now owns 8 rows
// and runs BOTH roles: single gather pass accumulates {ga0=A@Pr.x (shared),
// ga1=A@Pr.y, hl0, hl1}; dense pipeline streams all 6 weight matrices
// (Wg0 8 chunks then Wg1 16 chunks, contiguous, one unroll-1 ping-pong
// chain -- R6's proven no-spill structure); cell0 epilogue between the two
// loops (stores overlap loop B). Grid 512 blocks -> 8 waves/CU (2/SIMD):
// accepted risk, traded for halved gather work + halved ELL/P traffic.
// History: R0 48.5us baseline; R1/R2 occupancy/bytes probes (TLP not the
// lever above 8 waves/CU; bytes real); R3 serial staging 61us; R4/R5
// unroll-hoist VGPR explosion (fixed by #pragma unroll 1); R6 42.4us.
// Per-row FP order identical to R6 (absmax jitter = k_build atomicAdd
// slot order only).
//
// GATE-QUAD mapping: lane j owns cols {j, j+64, j+128, j+192} = (i,f,o,g) of
// hidden unit j. One wave = 2 rows x 256 cols; full quad in one lane's
// float4 acc.
//   Wg[(k*2+m)*64+j]        = cell0 quads, m in {gcWh0, liWh0}   (8192 f4)
//   Wg[8192+(k*4+m)*64+j]   = cell1 quads, m in {gcWi1, liWi1, gcWh1, liWh1}
// ---------------------------------------------------------------------------
__launch_bounds__(256)
__global__ void k_prep(const float* gcbi0, const float* gcbh0,
                       const float* libi0, const float* libh0,
                       const float* gcbi1, const float* gcbh1,
                       const float* libi1, const float* libh1,
                       const float* gcWh0, const float* liWh0,
                       const float* gcWi1, const float* liWi1,
                       const float* gcWh1, const float* liWh1,
                       const float* gcWi0, const float* liWi0,
                       float* state, float4* Wg0, float4* Wg1,
                       float4* biasg0, float4* biasg1, float4* xq0) {
  int idx = blockIdx.x * 256 + threadIdx.x;
  int stride = gridDim.x * 256;
  for (int i = idx; i < 6 * NH; i += stride) state[i] = 0.0f;  // P0,P1,c0,c1
  for (int i = idx; i < 64 * 2 * 64; i += stride) {
    int j = i & 63, m = (i >> 6) & 1, k = i >> 7;
    const float* W = m ? liWh0 : gcWh0;
    Wg0[i] = make_float4(W[k * GG + j], W[k * GG + j + 64],
                         W[k * GG + j + 128], W[k * GG + j + 192]);
  }
  for (int i = idx; i < 64 * 4 * 64; i += stride) {
    int j = i & 63, m = (i >> 6) & 3, k = i >> 8;
    const float* W = (m == 0) ? gcWi1 : (m == 1) ? liWi1 : (m == 2) ? gcWh1 : liWh1;
    Wg1[i] = make_float4(W[k * GG + j], W[k * GG + j + 64],
                         W[k * GG + j + 128], W[k * GG + j + 192]);
  }
  if (idx < 64) {
    int j = idx;
    biasg0[j] = make_float4(
        gcbi0[j] + gcbh0[j] + libi0[j] + libh0[j],
        gcbi0[j + 64] + gcbh0[j + 64] + libi0[j + 64] + libh0[j + 64],
        gcbi0[j + 128] + gcbh0[j + 128] + libi0[j + 128] + libh0[j + 128],
        gcbi0[j + 192] + gcbh0[j + 192] + libi0[j + 192] + libh0[j + 192]);
    biasg1[j] = make_float4(
        gcbi1[j] + gcbh1[j] + libi1[j] + libh1[j],
        gcbi1[j + 64] + gcbh1[j + 64] + libi1[j + 64] + libh1[j + 64],
        gcbi1[j + 128] + gcbh1[j + 128] + libi1[j + 128] + libh1[j + 128],
        gcbi1[j + 192] + gcbh1[j + 192] + libi1[j + 192] + libh1[j + 192]);
  } else if (idx < 320) {
    int i = idx - 64;           // i = m*64 + j
    int j = i & 63, m = i >> 6; // m: 0,1 -> gcWi0 row 0/1; 2,3 -> liWi0 row 0/1
    const float* W = (m < 2) ? gcWi0 : liWi0;
    int kk = m & 1;
    xq0[i] = make_float4(W[kk * GG + j], W[kk * GG + j + 64],
                         W[kk * GG + j + 128], W[kk * GG + j + 192]);
  }
}

// ---------------------------------------------------------------------------
// Single adj pass: raw ELL (incl. +I diag) + dinv. Zero-fills ALL CAP slots
// (re-poison semantics: padding must be (col=0, val=0)). cnt padded to x8.
// ---------------------------------------------------------------------------
__launch_bounds__(256)
__global__ void k_build(const float* adj, float* dinv,
                        int* ell_col, float* ell_val, int* ell_cnt) {
  int r = blockIdx.x;
  __shared__ int cnt;
  __shared__ float red[256];
  if (threadIdx.x == 0) cnt = 0;
  __syncthreads();
  const float* row = adj + (size_t)r * NN;
  float s = 0.0f;
  for (int c = threadIdx.x; c < NN; c += 256) {
    float a = row[c];
    if (c == r) a += 1.0f;   // A = adj + I
    s += a;
    if (a != 0.0f) {
      int pos = atomicAdd(&cnt, 1);
      if (pos < CAP) {
        ell_col[(size_t)r * CAP + pos] = c;
        ell_val[(size_t)r * CAP + pos] = a;
      }
    }
  }
  red[threadIdx.x] = s;
  __syncthreads();
  for (int st = 128; st > 0; st >>= 1) {
    if (threadIdx.x < st) red[threadIdx.x] += red[threadIdx.x + st];
    __syncthreads();
  }
  int n = cnt < CAP ? cnt : CAP;
  for (int j = n + (int)threadIdx.x; j < CAP; j += 256) {
    ell_col[(size_t)r * CAP + j] = 0;
    ell_val[(size_t)r * CAP + j] = 0.0f;
  }
  if (threadIdx.x == 0) {
    int npad = (n + 7) & ~7;
    if (npad > CAP) npad = CAP;
    ell_cnt[r] = npad;
    dinv[r] = 1.0f / sqrtf(red[0]);  // rowsum + 1 >= 1
  }
}

__launch_bounds__(256)
__global__ void k_scale(const float* dinv, const int* ell_col, float* ell_val) {
  int idx = blockIdx.x * 256 + threadIdx.x;  // over NN*CAP
  int r = idx / CAP;
  if (r >= NN) return;
  float v = ell_val[idx];
  if (v != 0.0f) ell_val[idx] = v * dinv[r] * dinv[ell_col[idx]];
}

// ---------------------------------------------------------------------------
// Precompute gax[t][r][c] = (A @ x_t)[r][c]. Block = (t, 512-row segment).
// ---------------------------------------------------------------------------
__launch_bounds__(256)
__global__ void k_gax(const float* x, const int* ell_col, const float* ell_val,
                      const int* ell_cnt, float* gax) {
  int t = blockIdx.x >> 3;
  int seg = blockIdx.x & 7;
  __shared__ float xs[NN * 2];
  const float* xt = x + (size_t)t * NN * 2;
  for (int i = threadIdx.x; i < NN * 2; i += 256) xs[i] = xt[i];
  __syncthreads();
  int base = seg * 512 * 2;
  for (int oo = threadIdx.x; oo < 512 * 2; oo += 256) {
    int o = base + oo;
    int r = o >> 1, cmp = o & 1;
    int cnt = ell_cnt[r];
    const int* cp = ell_col + (size_t)r * CAP;
    const float* vp = ell_val + (size_t)r * CAP;
    float acc = 0.0f;
    for (int j = 0; j < cnt; j += 4) {
      acc += vp[j]     * xs[cp[j]     * 2 + cmp];
      acc += vp[j + 1] * xs[cp[j + 1] * 2 + cmp];
      acc += vp[j + 2] * xs[cp[j + 2] * 2 + cmp];
      acc += vp[j + 3] * xs[cp[j + 3] * 2 + cmp];
    }
    gax[(size_t)t * NN * 2 + o] = acc;
  }
}

// ---------------------------------------------------------------------------
// Merged step kernel: one block = 8 rows = 4 waves x 2 rows, BOTH roles.
// Phase 1: single gather {ga0=A@Pr.x, ga1=A@Pr.y, hl0, hl1}.
// Phase 2: loop A = Wg0 chunks 0..7 (acc0); cell0 epilogue; loop B = Wg1
// chunks (acc1); cell1 epilogue. One continuous unroll-1 ping-pong prefetch
// chain across both loops. 2 x 16 KB LDS.
// ---------------------------------------------------------------------------
__launch_bounds__(256)
__global__ void k_cells(int c0on, int c1on,
                        const int* __restrict__ ell_col,
                        const float* __restrict__ ell_val,
                        const int* __restrict__ ell_cnt,
                        const float2* __restrict__ Pr, float* __restrict__ Pw,
                        float* __restrict__ c0, float* __restrict__ c1,
                        const float* __restrict__ xt, const float* __restrict__ gaxt,
                        const float4* __restrict__ Wg,
                        const float4* __restrict__ biasg0,
                        const float4* __restrict__ xq0,
                        const float4* __restrict__ biasg1) {
  __shared__ float4 wbuf[2048];  // 2 x 16 KB ping-pong
  const int tid = threadIdx.x;
  const int wave = tid >> 6, lane = tid & 63;
  const int r0 = blockIdx.x * 8 + wave * 2;

  // chunk-0 prefetch: completes under the gather phase
  const float4* pf = Wg + tid;
  float4 st0 = pf[0], st1 = pf[256], st2 = pf[512], st3 = pf[768];
  pf += 1024;

  // early c-state loads (latency hidden under gather)
  float cprev0[2], cprev1[2];
#pragma unroll
  for (int rr = 0; rr < 2; rr++) {
    size_t gi = (size_t)(r0 + rr) * HH + lane;
    cprev0[rr] = c0[gi];
    cprev1[rr] = c1[gi];
  }

  int myc[2][3]; float myv[2][3]; int cnts[2];
#pragma unroll
  for (int rr = 0; rr < 2; rr++) {
    int r = r0 + rr;
    cnts[rr] = ell_cnt[r];
#pragma unroll
    for (int chk = 0; chk < 3; chk++) {
      myc[rr][chk] = ell_col[(size_t)r * CAP + chk * 64 + lane];
      myv[rr][chk] = ell_val[(size_t)r * CAP + chk * 64 + lane];
    }
  }

  // single gather pass: both float2 components
  float ga0[2], ga1[2], hl0[2], hl1[2];
#pragma unroll
  for (int rr = 0; rr < 2; rr++) {
    int cnt = cnts[rr];
    float a0 = 0.0f, a1 = 0.0f;
#pragma unroll
    for (int chk = 0; chk < 3; chk++) {
      int base = chk * 64;
      if (base < cnt) {
        int lim = cnt - base; if (lim > 64) lim = 64;  // multiple of 8
        int mc = myc[rr][chk]; float mv = myv[rr][chk];
        for (int m = 0; m < lim; m += 8) {
          float2 ld[8]; float vv[8];
#pragma unroll
          for (int i = 0; i < 8; i++) {
            int cc = bcast_i(mc, m + i);
            vv[i] = bcast_f(mv, m + i);
            ld[i] = Pr[(size_t)cc * 64 + lane];
          }
#pragma unroll
          for (int i = 0; i < 8; i++) {
            a0 += vv[i] * ld[i].x;
            a1 += vv[i] * ld[i].y;
          }
        }
      }
    }
    ga0[rr] = a0;   // A @ h0(k-1)  -- shared by cell0 (gcWh0) and cell1 (gcWi1)
    ga1[rr] = a1;   // A @ h1(k-2)  -- cell1 (gcWh1)
    float2 hh = Pr[(size_t)(r0 + rr) * 64 + lane];
    hl0[rr] = hh.x; // h0(k-1)      -- cell0 (liWh0) and cell1 (liWi1)
    hl1[rr] = hh.y; // h1(k-2)      -- cell1 (liWh1)
  }

  // accumulator inits
  float4 acc0[2], acc1[2];
  {
    float4 b = biasg0[lane];
    float4 qg0 = xq0[lane], qg1 = xq0[64 + lane];
    float4 ql0 = xq0[128 + lane], ql1 = xq0[192 + lane];
#pragma unroll
    for (int rr = 0; rr < 2; rr++) {
      float xx0 = xt[(size_t)(r0 + rr) * 2];
      float xx1 = xt[(size_t)(r0 + rr) * 2 + 1];
      float gg0 = gaxt[(size_t)(r0 + rr) * 2];
      float gg1 = gaxt[(size_t)(r0 + rr) * 2 + 1];
      acc0[rr].x = b.x + gg0 * qg0.x + gg1 * qg1.x + xx0 * ql0.x + xx1 * ql1.x;
      acc0[rr].y = b.y + gg0 * qg0.y + gg1 * qg1.y + xx0 * ql0.y + xx1 * ql1.y;
      acc0[rr].z = b.z + gg0 * qg0.z + gg1 * qg1.z + xx0 * ql0.z + xx1 * ql1.z;
      acc0[rr].w = b.w + gg0 * qg0.w + gg1 * qg1.w + xx0 * ql0.w + xx1 * ql1.w;
    }
    float4 b1 = biasg1[lane];
    acc1[0] = b1; acc1[1] = b1;
  }

  // stage chunk 0, enter pipeline
  wbuf[tid] = st0; wbuf[256 + tid] = st1;
  wbuf[512 + tid] = st2; wbuf[768 + tid] = st3;
  __syncthreads();
  int cur = 0;

  // loop A: Wg0 chunks (8 k's each); ALWAYS prefetch next (ch=7 pulls in
  // Wg1 chunk 0 so the chain crosses the loop boundary seamlessly)
#pragma unroll 1
  for (int ch = 0; ch < 8; ch++) {
    st0 = pf[0]; st1 = pf[256]; st2 = pf[512]; st3 = pf[768];
    pf += 1024;
    const float4* wb = wbuf + (cur << 10);
#pragma unroll
    for (int kk = 0; kk < 8; kk++) {
      int k = ch * 8 + kk;
      float4 w0 = wb[(kk * 2 + 0) * 64 + lane];
      float4 w1 = wb[(kk * 2 + 1) * 64 + lane];
#pragma unroll
      for (int rr = 0; rr < 2; rr++) {
        float a0 = bcast_f(ga0[rr], k);
        float a1 = bcast_f(hl0[rr], k);
        acc0[rr].x += a0 * w0.x + a1 * w1.x;
        acc0[rr].y += a0 * w0.y + a1 * w1.y;
        acc0[rr].z += a0 * w0.z + a1 * w1.z;
        acc0[rr].w += a0 * w0.w + a1 * w1.w;
      }
    }
    cur ^= 1;
    float4* dst = wbuf + (cur << 10) + tid;
    dst[0] = st0; dst[256] = st1; dst[512] = st2; dst[768] = st3;
    __syncthreads();  // writes visible; all waves past chunk ch
  }

  // cell0 epilogue: stores issued here overlap loop B
  if (c0on) {
#pragma unroll
    for (int rr = 0; rr < 2; rr++) {
      size_t gi = (size_t)(r0 + rr) * HH + lane;
      float si = 1.0f / (1.0f + __expf(-acc0[rr].x));
      float sf = 1.0f / (1.0f + __expf(-acc0[rr].y));
      float so = 1.0f / (1.0f + __expf(-acc0[rr].z));
      float cn = sf * cprev0[rr] + si * tanhf(acc0[rr].w);
      float hn = so * tanhf(cn);
      c0[gi] = cn;
      Pw[gi * 2 + 0] = hn;
    }
  }

  // loop B: Wg1 chunks (4 k's each); buf[cur] already holds Wg1 chunk 0
  if (c1on) {
#pragma unroll 1
    for (int ch = 0; ch < 16; ch++) {
      if (ch + 1 < 16) {
        st0 = pf[0]; st1 = pf[256]; st2 = pf[512]; st3 = pf[768];
        pf += 1024;
      }
      const float4* wb = wbuf + (cur << 10);
#pragma unroll
      for (int kk = 0; kk < 4; kk++) {
        int k = ch * 4 + kk;
        float4 w0 = wb[(kk * 4 + 0) * 64 + lane];
        float4 w1 = wb[(kk * 4 + 1) * 64 + lane];
        float4 w2 = wb[(kk * 4 + 2) * 64 + lane];
        float4 w3 = wb[(kk * 4 + 3) * 64 + lane];
#pragma unroll
        for (int rr = 0; rr < 2; rr++) {
          float a0 = bcast_f(ga0[rr], k);   // (A@h0new)  -> gcWi1
          float a1 = bcast_f(hl0[rr], k);   // h0new      -> liWi1
          float a2 = bcast_f(ga1[rr], k);   // (A@h1old)  -> gcWh1
          float a3 = bcast_f(hl1[rr], k);   // h1old      -> liWh1
          acc1[rr].x += a0 * w0.x + a1 * w1.x + a2 * w2.x + a3 * w3.x;
          acc1[rr].y += a0 * w0.y + a1 * w1.y + a2 * w2.y + a3 * w3.y;
          acc1[rr].z += a0 * w0.z + a1 * w1.z + a2 * w2.z + a3 * w3.z;
          acc1[rr].w += a0 * w0.w + a1 * w1.w + a2 * w2.w + a3 * w3.w;
        }
      }
      if (ch + 1 < 16) {
        cur ^= 1;
        float4* dst = wbuf + (cur << 10) + tid;
        dst[0] = st0; dst[256] = st1; dst[512] = st2; dst[768] = st3;
        __syncthreads();
      }
    }
#pragma unroll
    for (int rr = 0; rr < 2; rr++) {
      size_t gi = (size_t)(r0 + rr) * HH + lane;
      float si = 1.0f / (1.0f + __expf(-acc1[rr].x));
      float sf = 1.0f / (1.0f + __expf(-acc1[rr].y));
      float so = 1.0f / (1.0f + __expf(-acc1[rr].z));
      float cn = sf * cprev1[rr] + si * tanhf(acc1[rr].w);
      float hn = so * tanhf(cn);
      c1[gi] = cn;
      Pw[gi * 2 + 1] = hn;
    }
  }
}

// ---------------------------------------------------------------------------
// Output projection: out[r,p] = h1[r,:] @ outW[:,p] + outb[p].
// h1 final = P0[..][1] (launch 48 writes P[0].y).
// ---------------------------------------------------------------------------
__launch_bounds__(256)
__global__ void k_out(const float* __restrict__ P0, const float* __restrict__ outW,
                      const float* __restrict__ outb, float* __restrict__ out) {
  int idx = blockIdx.x * 256 + threadIdx.x;
  if (idx >= NN * PP) return;
  int r = idx / PP, p = idx - r * PP;
  float acc = outb[p];
  const float* hrow = P0 + (size_t)r * 128;
#pragma unroll 16
  for (int k = 0; k < HH; k++) acc += hrow[k * 2 + 1] * outW[k * PP + p];
  out[idx] = acc;
}

extern "C" void kernel_launch(void* const* d_in, const int* in_sizes, int n_in,
                              void* d_out, int out_size, void* d_ws, size_t ws_size,
                              hipStream_t stream) {
  const float* x     = (const float*)d_in[0];
  const float* adj   = (const float*)d_in[1];
  const float* gcWi0 = (const float*)d_in[2];
  const float* gcbi0 = (const float*)d_in[3];
  const float* gcWh0 = (const float*)d_in[4];
  const float* gcbh0 = (const float*)d_in[5];
  const float* liWi0 = (const float*)d_in[6];
  const float* libi0 = (const float*)d_in[7];
  const float* liWh0 = (const float*)d_in[8];
  const float* libh0 = (const float*)d_in[9];
  const float* gcWi1 = (const float*)d_in[10];
  const float* gcbi1 = (const float*)d_in[11];
  const float* gcWh1 = (const float*)d_in[12];
  const float* gcbh1 = (const float*)d_in[13];
  const float* liWi1 = (const float*)d_in[14];
  const float* libi1 = (const float*)d_in[15];
  const float* liWh1 = (const float*)d_in[16];
  const float* libh1 = (const float*)d_in[17];
  const float* outW  = (const float*)d_in[18];
  const float* outb  = (const float*)d_in[19];

  char* ws = (char*)d_ws;
  size_t off = 0;
  auto carve = [&](size_t bytes) {
    void* p = ws + off;
    off += (bytes + 255) & ~(size_t)255;
    return p;
  };
  float*  dinv    = (float*)carve((size_t)NN * 4);
  int*    ell_col = (int*)carve((size_t)NN * CAP * 4);
  float*  ell_val = (float*)carve((size_t)NN * CAP * 4);
  int*    ell_cnt = (int*)carve((size_t)NN * 4);
  float*  state   = (float*)carve((size_t)6 * NH * 4);  // P0,P1 (2NH each), c0, c1
  float*  gax     = (float*)carve((size_t)TT * NN * 2 * 4);
  float4* Wgm     = (float4*)carve((size_t)(8192 + 16384) * 16);  // Wg0|Wg1 contiguous
  float4* biasg0  = (float4*)carve((size_t)64 * 16);
  float4* biasg1  = (float4*)carve((size_t)64 * 16);
  float4* xq0     = (float4*)carve((size_t)256 * 16);

  float4* Wg0 = Wgm;
  float4* Wg1 = Wgm + 8192;
  float* P[2] = {state, state + 2 * NH};
  float* c0 = state + 4 * NH;
  float* c1 = state + 5 * NH;

  k_prep<<<512, 256, 0, stream>>>(gcbi0, gcbh0, libi0, libh0,
                                  gcbi1, gcbh1, libi1, libh1,
                                  gcWh0, liWh0, gcWi1, liWi1, gcWh1, liWh1,
                                  gcWi0, liWi0,
                                  state, Wg0, Wg1, biasg0, biasg1, xq0);
  k_build<<<NN, 256, 0, stream>>>(adj, dinv, ell_col, ell_val, ell_cnt);
  k_scale<<<(NN * CAP) / 256, 256, 0, stream>>>(dinv, ell_col, ell_val);
  k_gax<<<TT * 8, 256, 0, stream>>>(x, ell_col, ell_val, ell_cnt, gax);

  // Merged step loop: launch k runs {cell0(k) + cell1(k-1)} per 8-row block.
  // Launch k reads P[(k&1)^1], writes P[k&1].
  for (int k = 0; k <= TT; k++) {
    int A = k & 1;
    int c0on = (k < TT) ? 1 : 0;
    int c1on = (k > 0) ? 1 : 0;
    int tx = (k < TT) ? k : (TT - 1);              // xt/gaxt unused when k==TT
    k_cells<<<NN / 8, 256, 0, stream>>>(
        c0on, c1on, ell_col, ell_val, ell_cnt,
        (const float2*)P[A ^ 1], P[A], c0, c1,
        x + (size_t)tx * NN * 2, gax + (size_t)tx * NN * 2,
        Wgm, biasg0, xq0, biasg1);
  }

  // Launch 48 (A=0) wrote h1(47) into P[0].y
  k_out<<<(NN * PP + 255) / 256, 256, 0, stream>>>(P[0], outW, outb, (float*)d_out);
}